// Round 9
// baseline (2200.691 us; speedup 1.0000x reference)
//
#include <hip/hip_runtime.h>
#include <cstdint>
#include <climits>

#define N 8192
#define D 64
#define H 128
#define O 64
#define KNB 16
#define NE (N*KNB)        // 131072
#define ETOT (NE + N)     // 139264
#define OUT0 (N*D)        // 524288
#define NSPL 32           // j-splits (chunks)
#define JSPAN 256         // j's per chunk (N/NSPL)
#define JTILE 128         // j-rows staged in LDS per tile (32 KB)
#define TCH 4             // stored top-T per chunk

__device__ __forceinline__ float bf2f(unsigned short u){
    union { unsigned int u; float f; } v; v.u = ((unsigned int)u) << 16; return v.f;
}
__device__ __forceinline__ unsigned short f2bf(float f){
    union { float f; unsigned int u; } v; v.f = f;
    unsigned int r = v.u + 0x7FFFu + ((v.u >> 16) & 1u);   // RNE
    return (unsigned short)(r >> 16);
}

#define PIN4(v) asm volatile("" : "+v"((v).x), "+v"((v).y), "+v"((v).z), "+v"((v).w))

// ---------------- dtype probe: 1=bf16 inputs, 0=fp32 inputs ----------------
__global__ void k_probe(const unsigned short* __restrict__ x, int* __restrict__ flag){
    __shared__ int cnt;
    if (threadIdx.x == 0) cnt = 0;
    __syncthreads();
    unsigned short u = x[2*threadIdx.x];
    int e = (u >> 7) & 0xFF;
    int ok = (u == 0) || (e >= 0x60 && e <= 0x85);
    unsigned long long m = __ballot(ok);
    if ((threadIdx.x & 63) == 0) atomicAdd(&cnt, __popcll(m));
    __syncthreads();
    if (threadIdx.x == 0) *flag = (cnt >= 128) ? 1 : 0;
}

// ---------------- x convert -> fp32 ----------------
__global__ void k_cvt(const void* __restrict__ src, float* __restrict__ dst,
                      int n, const int* __restrict__ flag){
    int i = blockIdx.x*256 + threadIdx.x;
    if (i >= n) return;
    if (*flag) dst[i] = bf2f(((const unsigned short*)src)[i]);
    else       dst[i] = ((const float*)src)[i];
}

// ---------------- fused param convert (10 tensors, one launch) ----------------
__global__ void k_cvtp(const void* s1, const void* s2, const void* s3, const void* s4,
                       const void* s5, const void* s6, const void* s7, const void* s8,
                       const void* s9, const void* s10,
                       float* d1, float* d2, float* d3, float* d4, float* d5,
                       float* d6, float* d7, float* d8, float* d9, float* d10,
                       const int* __restrict__ flag){
    int id = blockIdx.x*256 + threadIdx.x;
    const void* s; float* d; int off;
    if      (id <  8192){ s = s1;  d = d1;  off = id; }
    else if (id <  8320){ s = s2;  d = d2;  off = id - 8192; }
    else if (id <  8448){ s = s3;  d = d3;  off = id - 8320; }
    else if (id <  8576){ s = s4;  d = d4;  off = id - 8448; }
    else if (id < 16768){ s = s5;  d = d5;  off = id - 8576; }
    else if (id < 16832){ s = s6;  d = d6;  off = id - 16768; }
    else if (id < 16896){ s = s7;  d = d7;  off = id - 16832; }
    else if (id < 16960){ s = s8;  d = d8;  off = id - 16896; }
    else if (id < 21056){ s = s9;  d = d9;  off = id - 16960; }
    else if (id < 21120){ s = s10; d = d10; off = id - 21056; }
    else return;
    if (*flag) d[off] = bf2f(((const unsigned short*)s)[off]);
    else       d[off] = ((const float*)s)[off];
}

// ---------------- row norms: EXACT numpy fp32 pairwise semantics ----------------
__global__ void k_prep(const float* __restrict__ xf, float* __restrict__ nrmf){
    int i = blockIdx.x*64 + threadIdx.x;
    const float* xr = xf + i*D;
    float r[8];
    #pragma unroll
    for (int q = 0; q < 8; ++q) r[q] = __fmul_rn(xr[q], xr[q]);
    #pragma unroll
    for (int b = 8; b < 64; b += 8)
        #pragma unroll
        for (int q = 0; q < 8; ++q)
            r[q] = __fadd_rn(r[q], __fmul_rn(xr[b+q], xr[b+q]));
    float s = __fadd_rn(__fadd_rn(__fadd_rn(r[0],r[1]), __fadd_rn(r[2],r[3])),
                        __fadd_rn(__fadd_rn(r[4],r[5]), __fadd_rn(r[6],r[7])));
    nrmf[i] = __fsqrt_rn(s);
}

// =====================================================================
// Single-scan exact top-k with per-chunk top-4 certificate.
// k_scan4 keeps the top-4 (value,idx) per 256-j chunk per query (LDS-
// broadcast j-rows — round-8-verified structure; DS-pipe-bound at ~181us,
// so the deeper insert is mostly free). k_sel16 then takes the top-16 of
// the 32x4 candidate union under the exact (value desc, idx asc)
// comparator. CERTIFICATE: any element NOT stored for chunk c ranks
// strictly below c's stored 4th. So if c's 4th ranks <= the provisional
// 16th (a16), every hidden element of c ranks < a16 and the union top-16
// is the true top-16. Otherwise chunk c is rescanned serially (exact
// same chain) — probability ~C(16,4)/32^3 ~ 4% of queries on random data.
// Sim chain (bitwise-stable, operand-source independent):
//   a = fma-chain k=0..63; den = fadd(fmul(ni,nj),1e-8); s = fdiv(a,den).
// This deletes the entire second scan pass (k_filter, ~175us) plus
// k_vsel/k_zero/k_select.
// =====================================================================

__global__ __launch_bounds__(256, 2) void k_scan4(const float* __restrict__ xf,
                                                  const float* __restrict__ nrmf,
                                                  float* __restrict__ chV,
                                                  int* __restrict__ chI){
    __shared__ float sB[JTILE*64];   // 32 KB j-row tile
    __shared__ float sN[JTILE];

    int tid = threadIdx.x;
    int grp = blockIdx.x & 31;        // 32 query groups of 256
    int split = blockIdx.x >> 5;      // 32 chunks
    int i = grp*256 + tid;
    int jbase = split*JSPAN;

    const float4* xip = (const float4*)(xf + (size_t)i*D);
    float4 xi4[16];
    #pragma unroll
    for (int c = 0; c < 16; ++c) xi4[c] = xip[c];
    #pragma unroll
    for (int c = 0; c < 16; ++c) PIN4(xi4[c]);
    float ni = nrmf[i];

    float lv[TCH]; int li[TCH];
    #pragma unroll
    for (int r = 0; r < TCH; ++r){ lv[r] = -3.0e38f; li[r] = INT_MAX; }

    for (int t = 0; t < JSPAN/JTILE; ++t){
        int jt = jbase + t*JTILE;
        __syncthreads();   // previous tile fully consumed
        #pragma unroll
        for (int u = 0; u < (JTILE*16)/256; ++u){
            int idx = u*256 + tid;
            ((float4*)sB)[idx] = ((const float4*)xf)[(size_t)jt*16 + idx];
        }
        if (tid < JTILE) sN[tid] = nrmf[jt + tid];
        __syncthreads();

        for (int jj = 0; jj < JTILE; ++jj){
            int j = jt + jj;
            const float4* B4 = (const float4*)(sB + jj*64);   // uniform -> broadcast
            float nj = sN[jj];
            float a = 0.0f;
            #pragma unroll
            for (int c = 0; c < 16; ++c){
                float4 b = B4[c]; float4 xa = xi4[c];
                a = __fmaf_rn(b.x, xa.x, a);
                a = __fmaf_rn(b.y, xa.y, a);
                a = __fmaf_rn(b.z, xa.z, a);
                a = __fmaf_rn(b.w, xa.w, a);
            }
            float den = __fadd_rn(__fmul_rn(ni, nj), 1e-8f);
            float thr = lv[TCH-1]*den;
            // conservative prefilter (margin >> fdiv rounding), exact recheck
            if (j != i && a > __fmaf_rn(fabsf(thr), -1e-6f, thr)){
                float s0 = __fdiv_rn(a, den);
                if (s0 > lv[TCH-1]){   // strict >: ties keep earlier idx (idx-asc rank)
                    lv[TCH-1] = s0; li[TCH-1] = j;
                    #pragma unroll
                    for (int r = TCH-1; r > 0; --r){
                        if (lv[r] > lv[r-1]){
                            float tv = lv[r]; lv[r] = lv[r-1]; lv[r-1] = tv;
                            int ti = li[r]; li[r] = li[r-1]; li[r-1] = ti;
                        }
                    }
                }
            }
        }
    }
    // transposed layout: [(split*4+r)*N + i] — coalesced store AND read
    #pragma unroll
    for (int r = 0; r < TCH; ++r){
        chV[(size_t)(split*TCH + r)*N + i] = lv[r];
        chI[(size_t)(split*TCH + r)*N + i] = li[r];
    }
}

// ---- exact top-16 of the candidate union; rescan flagged chunks ----
__global__ __launch_bounds__(128) void k_sel16(const float* __restrict__ xf,
                                               const float* __restrict__ nrmf,
                                               const float* __restrict__ chV,
                                               const int* __restrict__ chI,
                                               int* __restrict__ topIdx,
                                               float* __restrict__ ewArr){
    int q = blockIdx.x*128 + threadIdx.x;

    float lv[16]; int li[16];
    #pragma unroll
    for (int r = 0; r < 16; ++r){ lv[r] = -3.0e38f; li[r] = INT_MAX; }

    // pass 1: provisional top-16 from all 128 candidates (full comparator)
    for (int c = 0; c < NSPL; ++c){
        #pragma unroll
        for (int r = 0; r < TCH; ++r){
            float v = chV[(size_t)(c*TCH + r)*N + q];
            int  id = chI[(size_t)(c*TCH + r)*N + q];
            if (v > lv[15] || (v == lv[15] && id < li[15])){
                lv[15] = v; li[15] = id;
                #pragma unroll
                for (int k = 15; k > 0; --k){
                    if (lv[k] > lv[k-1] || (lv[k] == lv[k-1] && li[k] < li[k-1])){
                        float tv = lv[k]; lv[k] = lv[k-1]; lv[k-1] = tv;
                        int ti = li[k]; li[k] = li[k-1]; li[k-1] = ti;
                    }
                }
            }
        }
    }
    // flag chunks whose stored 4th ranks above the provisional 16th
    unsigned int flags = 0;
    for (int c = 0; c < NSPL; ++c){
        float v4 = chV[(size_t)(c*TCH + TCH-1)*N + q];
        int  i4 = chI[(size_t)(c*TCH + TCH-1)*N + q];
        if (v4 > lv[15] || (v4 == lv[15] && i4 < li[15])) flags |= (1u << c);
    }
    if (flags){
        // rare path: rebuild, fully rescanning flagged chunks (exact chain)
        #pragma unroll
        for (int r = 0; r < 16; ++r){ lv[r] = -3.0e38f; li[r] = INT_MAX; }
        const float* xr = xf + (size_t)q*D;
        float ni = nrmf[q];
        for (int c = 0; c < NSPL; ++c){
            if ((flags >> c) & 1u){
                for (int j = c*JSPAN; j < c*JSPAN + JSPAN; ++j){
                    if (j == q) continue;
                    const float* br = xf + (size_t)j*D;
                    float a = 0.0f;
                    for (int k = 0; k < 64; ++k)
                        a = __fmaf_rn(br[k], xr[k], a);
                    float den = __fadd_rn(__fmul_rn(ni, nrmf[j]), 1e-8f);
                    float s0 = __fdiv_rn(a, den);
                    if (s0 > lv[15] || (s0 == lv[15] && j < li[15])){
                        lv[15] = s0; li[15] = j;
                        #pragma unroll
                        for (int k = 15; k > 0; --k){
                            if (lv[k] > lv[k-1] || (lv[k] == lv[k-1] && li[k] < li[k-1])){
                                float tv = lv[k]; lv[k] = lv[k-1]; lv[k-1] = tv;
                                int ti = li[k]; li[k] = li[k-1]; li[k-1] = ti;
                            }
                        }
                    }
                }
            } else {
                #pragma unroll
                for (int r = 0; r < TCH; ++r){
                    float v = chV[(size_t)(c*TCH + r)*N + q];
                    int  id = chI[(size_t)(c*TCH + r)*N + q];
                    if (v > lv[15] || (v == lv[15] && id < li[15])){
                        lv[15] = v; li[15] = id;
                        #pragma unroll
                        for (int k = 15; k > 0; --k){
                            if (lv[k] > lv[k-1] || (lv[k] == lv[k-1] && li[k] < li[k-1])){
                                float tv = lv[k]; lv[k] = lv[k-1]; lv[k-1] = tv;
                                int ti = li[k]; li[k] = li[k-1]; li[k-1] = ti;
                            }
                        }
                    }
                }
            }
        }
    }
    #pragma unroll
    for (int sel = 0; sel < KNB; ++sel){
        topIdx[q*KNB + sel] = li[sel];
        ewArr [q*KNB + sel] = (lv[sel] > 0.5f) ? lv[sel] : 0.0f;
    }
}

// ---------------- degree / dinv ----------------
__global__ void k_deg_init(double* __restrict__ degD){
    int j = blockIdx.x*blockDim.x + threadIdx.x;
    if (j < N) degD[j] = 2.0;
}
__global__ void k_deg_scatter(const int* __restrict__ topIdx, const float* __restrict__ ewArr,
                              double* __restrict__ degD){
    int e = blockIdx.x*blockDim.x + threadIdx.x;
    if (e < NE){
        float w = ewArr[e];
        if (w > 0.0f) atomicAdd(&degD[topIdx[e]], (double)w);
    }
}
__global__ void k_dinv(const double* __restrict__ degD, float* __restrict__ dinv){
    int j = blockIdx.x*blockDim.x + threadIdx.x;
    if (j < N) dinv[j] = (float)(1.0 / sqrt(degD[j]));
}

// ---------------- dense matmuls ----------------
__global__ void k_gemm1(const float* __restrict__ xf, const float* __restrict__ W1,
                        float* __restrict__ h1){
    int id = blockIdx.x*256 + threadIdx.x;
    int i = id >> 7; int f = id & (H-1);
    const float* xr = xf + i*D;
    float acc = 0.f;
    #pragma unroll
    for (int k = 0; k < D; ++k) acc += xr[k] * W1[k*H + f];
    h1[id] = acc;
}
__global__ void k_gemm2(const float* __restrict__ z1, const float* __restrict__ W2,
                        float* __restrict__ h2){
    int id = blockIdx.x*256 + threadIdx.x;
    int i = id >> 6; int f = id & (O-1);
    const float* zr = z1 + i*H;
    float acc = 0.f;
    #pragma unroll
    for (int k = 0; k < H; ++k) acc += zr[k] * W2[k*O + f];
    h2[id] = acc;
}
__global__ void k_proj(const float* __restrict__ z2, const float* __restrict__ Wp,
                       const float* __restrict__ bp, float* __restrict__ z3){
    int id = blockIdx.x*256 + threadIdx.x;
    int i = id >> 6; int f = id & (D-1);
    const float* zr = z2 + i*O;
    float acc = bp[f];
    #pragma unroll
    for (int k = 0; k < O; ++k) acc += zr[k] * Wp[k*D + f];
    z3[id] = acc;
}

// ---------------- GCN aggregation ----------------
template<int F>
__global__ void k_agg_init(const float* __restrict__ h, const float* __restrict__ dinv,
                           float* __restrict__ agg){
    int id = blockIdx.x*256 + threadIdx.x;
    int j = id / F;
    float dj = dinv[j];
    agg[id] = 2.f * dj * dj * h[id];
}
template<int F>
__global__ void k_agg_scat(const int* __restrict__ topIdx, const float* __restrict__ ewArr,
                           const float* __restrict__ dinv, const float* __restrict__ h,
                           float* __restrict__ agg){
    int e = blockIdx.x; int f = threadIdx.x;
    float w = ewArr[e];
    if (w == 0.f) return;
    int s = e >> 4;
    int dn = topIdx[e];
    float c = dinv[s] * w * dinv[dn];
    atomicAdd(&agg[dn*F + f], c * h[s*F + f]);
}

// ---------------- bias + relu + layernorm ----------------
__global__ void k_post128(const float* __restrict__ agg, const float* __restrict__ b,
                          const float* __restrict__ g, const float* __restrict__ be,
                          float* __restrict__ z){
    __shared__ double s2[2];
    __shared__ double s3[2];
    int i = blockIdx.x; int f = threadIdx.x;
    float v = agg[i*H + f] + b[f];
    v = v > 0.f ? v : 0.f;
    int wid = f >> 6;
    double d = (double)v;
    for (int off = 32; off > 0; off >>= 1) d += __shfl_xor(d, off);
    if ((f & 63) == 0) s2[wid] = d;
    __syncthreads();
    double mu = (s2[0] + s2[1]) * (1.0/128.0);
    double dv = (double)v - mu;
    double qq = dv * dv;
    for (int off = 32; off > 0; off >>= 1) qq += __shfl_xor(qq, off);
    if ((f & 63) == 0) s3[wid] = qq;
    __syncthreads();
    double var = (s3[0] + s3[1]) * (1.0/128.0);
    double rs = 1.0 / sqrt(var + 1e-5);
    z[i*H + f] = (float)(dv * rs * (double)g[f] + (double)be[f]);
}
__global__ void k_post64(const float* __restrict__ agg, const float* __restrict__ b,
                         const float* __restrict__ g, const float* __restrict__ be,
                         float* __restrict__ z){
    int i = blockIdx.x; int f = threadIdx.x;
    float v = agg[i*O + f] + b[f];
    v = v > 0.f ? v : 0.f;
    double d = (double)v;
    for (int off = 32; off > 0; off >>= 1) d += __shfl_xor(d, off);
    double mu = d * (1.0/64.0);
    double dv = (double)v - mu;
    double qq = dv * dv;
    for (int off = 32; off > 0; off >>= 1) qq += __shfl_xor(qq, off);
    double var = qq * (1.0/64.0);
    double rs = 1.0 / sqrt(var + 1e-5);
    z[i*O + f] = (float)(dv * rs * (double)g[f] + (double)be[f]);
}

// ---------------- fused output store + edges (flag-branched dtype) ----------------
__global__ void k_out(const float* __restrict__ z3, const int* __restrict__ topIdx,
                      const float* __restrict__ ewArr, void* __restrict__ outp,
                      const int* __restrict__ flag){
    int id = blockIdx.x*256 + threadIdx.x;
    if (id < OUT0){
        float v = z3[id];
        if (*flag) ((unsigned short*)outp)[id] = f2bf(v);
        else       ((float*)outp)[id] = v;
        return;
    }
    int e = id - OUT0;
    if (e >= ETOT) return;
    int s, dn; float w;
    if (e < NE){ s = e >> 4; dn = topIdx[e]; w = ewArr[e]; }
    else       { s = e - NE; dn = s;        w = 1.0f; }
    if (*flag){
        unsigned short* o = (unsigned short*)outp;
        o[OUT0 + e]          = f2bf((float)s);
        o[OUT0 + ETOT + e]   = f2bf((float)dn);
        o[OUT0 + 2*ETOT + e] = f2bf(w);
    } else {
        float* o = (float*)outp;
        o[OUT0 + e]          = (float)s;
        o[OUT0 + ETOT + e]   = (float)dn;
        o[OUT0 + 2*ETOT + e] = w;
    }
}

extern "C" void kernel_launch(void* const* d_in, const int* in_sizes, int n_in,
                              void* d_out, int out_size, void* d_ws, size_t ws_size,
                              hipStream_t stream){
    char* ws = (char*)d_ws;
    int*    flag   = (int*)   (ws + 0);
    float*  w1f    = (float*) (ws + 4096);
    float*  b1f    = (float*) (ws + 36864);
    float*  g1f    = (float*) (ws + 37376);
    float*  be1f   = (float*) (ws + 37888);
    float*  w2f    = (float*) (ws + 38400);
    float*  b2f    = (float*) (ws + 71168);
    float*  g2f    = (float*) (ws + 71424);
    float*  be2f   = (float*) (ws + 71680);
    float*  wpf    = (float*) (ws + 71936);
    float*  bpf    = (float*) (ws + 88320);
    float*  xf     = (float*) (ws + 98304);      // 2 MB          -> 2195456
    float*  nrmf   = (float*) (ws + 2195456);    // 32 KB         -> 2228224
    int*    topIdx = (int*)   (ws + 2260992);    // 512 KB        -> 2785280
    float*  ewArr  = (float*) (ws + 2785280);    // 512 KB        -> 3309568
    double* degD   = (double*)(ws + 3309568);    // 64 KB         -> 3375104
    float*  dinv   = (float*) (ws + 3375104);    // 32 KB         -> 3407872
    float*  h1     = (float*) (ws + 3407872);    // 4 MB          -> 7602176
    float*  agg1   = (float*) (ws + 7602176);    // 4 MB          -> 11796480
    float*  z1     = (float*) (ws + 11796480);   // 4 MB          -> 15990784
    float*  h2     = h1;
    float*  agg2   = agg1;
    float*  z2     = z1;
    float*  z3     = h1;

    // topk scratch overlaps h1/agg1 (dead until k_gemm1, which launches
    // after k_sel16 completes): chV 4 MB + chI 4 MB.
    float* chV = (float*)(ws + 3407872);
    int*   chI = (int*)  (ws + 7602176);

    k_probe<<<1, 256, 0, stream>>>((const unsigned short*)d_in[0], flag);
    k_cvt<<<(N*D+255)/256, 256, 0, stream>>>(d_in[0], xf,  N*D, flag);
    k_cvtp<<<(21120+255)/256, 256, 0, stream>>>(
        d_in[1], d_in[2], d_in[3], d_in[4], d_in[5],
        d_in[6], d_in[7], d_in[8], d_in[9], d_in[10],
        w1f, b1f, g1f, be1f, w2f, b2f, g2f, be2f, wpf, bpf, flag);

    k_prep<<<N/64, 64, 0, stream>>>(xf, nrmf);
    k_scan4<<<32*NSPL, 256, 0, stream>>>(xf, nrmf, chV, chI);
    k_sel16<<<N/128, 128, 0, stream>>>(xf, nrmf, chV, chI, topIdx, ewArr);

    k_deg_init<<<N/256, 256, 0, stream>>>(degD);
    k_deg_scatter<<<NE/256, 256, 0, stream>>>(topIdx, ewArr, degD);
    k_dinv<<<N/256, 256, 0, stream>>>(degD, dinv);

    k_gemm1<<<(N*H)/256, 256, 0, stream>>>(xf, w1f, h1);
    k_agg_init<H><<<(N*H)/256, 256, 0, stream>>>(h1, dinv, agg1);
    k_agg_scat<H><<<NE, H, 0, stream>>>(topIdx, ewArr, dinv, h1, agg1);
    k_post128<<<N, H, 0, stream>>>(agg1, b1f, g1f, be1f, z1);

    k_gemm2<<<(N*O)/256, 256, 0, stream>>>(z1, w2f, h2);
    k_agg_init<O><<<(N*O)/256, 256, 0, stream>>>(h2, dinv, agg2);
    k_agg_scat<O><<<NE, O, 0, stream>>>(topIdx, ewArr, dinv, h2, agg2);
    k_post64<<<N, O, 0, stream>>>(agg2, b2f, g2f, be2f, z2);

    k_proj<<<(N*D)/256, 256, 0, stream>>>(z2, wpf, bpf, z3);
    k_out<<<(OUT0+ETOT+255)/256, 256, 0, stream>>>(z3, topIdx, ewArr, d_out, flag);
}

// Round 10
// 1216.720 us; speedup vs baseline: 1.8087x; 1.8087x over previous
//
#include <hip/hip_runtime.h>
#include <cstdint>
#include <climits>

#define N 8192
#define D 64
#define H 128
#define O 64
#define KNB 16
#define NE (N*KNB)        // 131072
#define ETOT (NE + N)     // 139264
#define OUT0 (N*D)        // 524288
#define NSPL 32           // j-splits (chunks)
#define JSPAN 256         // j's per chunk (N/NSPL)
#define JTILE 128         // j-rows staged in LDS per tile (32 KB)
#define TCH 6             // stored top-T per chunk (certificate depth)

__device__ __forceinline__ float bf2f(unsigned short u){
    union { unsigned int u; float f; } v; v.u = ((unsigned int)u) << 16; return v.f;
}
__device__ __forceinline__ unsigned short f2bf(float f){
    union { float f; unsigned int u; } v; v.f = f;
    unsigned int r = v.u + 0x7FFFu + ((v.u >> 16) & 1u);   // RNE
    return (unsigned short)(r >> 16);
}

#define PIN4(v) asm volatile("" : "+v"((v).x), "+v"((v).y), "+v"((v).z), "+v"((v).w))

// ---------------- dtype probe: 1=bf16 inputs, 0=fp32 inputs ----------------
__global__ void k_probe(const unsigned short* __restrict__ x, int* __restrict__ flag){
    __shared__ int cnt;
    if (threadIdx.x == 0) cnt = 0;
    __syncthreads();
    unsigned short u = x[2*threadIdx.x];
    int e = (u >> 7) & 0xFF;
    int ok = (u == 0) || (e >= 0x60 && e <= 0x85);
    unsigned long long m = __ballot(ok);
    if ((threadIdx.x & 63) == 0) atomicAdd(&cnt, __popcll(m));
    __syncthreads();
    if (threadIdx.x == 0) *flag = (cnt >= 128) ? 1 : 0;
}

// ---------------- x convert -> fp32 ----------------
__global__ void k_cvt(const void* __restrict__ src, float* __restrict__ dst,
                      int n, const int* __restrict__ flag){
    int i = blockIdx.x*256 + threadIdx.x;
    if (i >= n) return;
    if (*flag) dst[i] = bf2f(((const unsigned short*)src)[i]);
    else       dst[i] = ((const float*)src)[i];
}

// ---------------- fused param convert (10 tensors, one launch) ----------------
__global__ void k_cvtp(const void* s1, const void* s2, const void* s3, const void* s4,
                       const void* s5, const void* s6, const void* s7, const void* s8,
                       const void* s9, const void* s10,
                       float* d1, float* d2, float* d3, float* d4, float* d5,
                       float* d6, float* d7, float* d8, float* d9, float* d10,
                       const int* __restrict__ flag){
    int id = blockIdx.x*256 + threadIdx.x;
    const void* s; float* d; int off;
    if      (id <  8192){ s = s1;  d = d1;  off = id; }
    else if (id <  8320){ s = s2;  d = d2;  off = id - 8192; }
    else if (id <  8448){ s = s3;  d = d3;  off = id - 8320; }
    else if (id <  8576){ s = s4;  d = d4;  off = id - 8448; }
    else if (id < 16768){ s = s5;  d = d5;  off = id - 8576; }
    else if (id < 16832){ s = s6;  d = d6;  off = id - 16768; }
    else if (id < 16896){ s = s7;  d = d7;  off = id - 16832; }
    else if (id < 16960){ s = s8;  d = d8;  off = id - 16896; }
    else if (id < 21056){ s = s9;  d = d9;  off = id - 16960; }
    else if (id < 21120){ s = s10; d = d10; off = id - 21056; }
    else return;
    if (*flag) d[off] = bf2f(((const unsigned short*)s)[off]);
    else       d[off] = ((const float*)s)[off];
}

// ---------------- row norms: EXACT numpy fp32 pairwise semantics ----------------
__global__ void k_prep(const float* __restrict__ xf, float* __restrict__ nrmf){
    int i = blockIdx.x*64 + threadIdx.x;
    const float* xr = xf + i*D;
    float r[8];
    #pragma unroll
    for (int q = 0; q < 8; ++q) r[q] = __fmul_rn(xr[q], xr[q]);
    #pragma unroll
    for (int b = 8; b < 64; b += 8)
        #pragma unroll
        for (int q = 0; q < 8; ++q)
            r[q] = __fadd_rn(r[q], __fmul_rn(xr[b+q], xr[b+q]));
    float s = __fadd_rn(__fadd_rn(__fadd_rn(r[0],r[1]), __fadd_rn(r[2],r[3])),
                        __fadd_rn(__fadd_rn(r[4],r[5]), __fadd_rn(r[6],r[7])));
    nrmf[i] = __fsqrt_rn(s);
}

// =====================================================================
// Single-scan exact top-k with per-chunk top-6 certificate.
// k_scan6: top-6 (value,idx) per 256-j chunk per query (LDS-broadcast
// j-rows, round-8-verified structure). k_sel16: exact top-16 of the 32x6
// union under the (value desc, idx asc) jax.lax.top_k comparator.
// CERTIFICATE: every element NOT stored for chunk c ranks strictly below
// c's stored 6th (proof: at drop time it ranked below the then-6th, whose
// rank only improves; idx-asc ties resolved by ascending-j scan order).
// So if no chunk's 6th ranks above the provisional 16th, the union top-16
// is the true top-16. ROUND-9 POST-MORTEM: TCH=4 fired the fallback for
// ~5% of queries => nearly EVERY 64-lane wave serialized a rescan, and the
// rolled scalar rescan loop was ~250cyc/element -> 2376us. TCH=6 makes
// P(fire) ~ 32*P(Bin(16,1/32)>=6) ~ 1.7e-4/query (~1-2 pairs per RUN),
// and the fallback is float4-vectorized (~50us worst-case) as a net.
// Sim chain (bitwise-stable, operand-source independent):
//   a = fma-chain k=0..63; den = fadd(fmul(ni,nj),1e-8); s = fdiv(a,den).
// =====================================================================

__global__ __launch_bounds__(256, 2) void k_scan6(const float* __restrict__ xf,
                                                  const float* __restrict__ nrmf,
                                                  float* __restrict__ chV,
                                                  int* __restrict__ chI){
    __shared__ float sB[JTILE*64];   // 32 KB j-row tile
    __shared__ float sN[JTILE];

    int tid = threadIdx.x;
    int grp = blockIdx.x & 31;        // 32 query groups of 256
    int split = blockIdx.x >> 5;      // 32 chunks
    int i = grp*256 + tid;
    int jbase = split*JSPAN;

    const float4* xip = (const float4*)(xf + (size_t)i*D);
    float4 xi4[16];
    #pragma unroll
    for (int c = 0; c < 16; ++c) xi4[c] = xip[c];
    #pragma unroll
    for (int c = 0; c < 16; ++c) PIN4(xi4[c]);
    float ni = nrmf[i];

    float lv[TCH]; int li[TCH];
    #pragma unroll
    for (int r = 0; r < TCH; ++r){ lv[r] = -3.0e38f; li[r] = INT_MAX; }

    for (int t = 0; t < JSPAN/JTILE; ++t){
        int jt = jbase + t*JTILE;
        __syncthreads();   // previous tile fully consumed
        #pragma unroll
        for (int u = 0; u < (JTILE*16)/256; ++u){
            int idx = u*256 + tid;
            ((float4*)sB)[idx] = ((const float4*)xf)[(size_t)jt*16 + idx];
        }
        if (tid < JTILE) sN[tid] = nrmf[jt + tid];
        __syncthreads();

        for (int jj = 0; jj < JTILE; ++jj){
            int j = jt + jj;
            const float4* B4 = (const float4*)(sB + jj*64);   // uniform -> broadcast
            float nj = sN[jj];
            float a = 0.0f;
            #pragma unroll
            for (int c = 0; c < 16; ++c){
                float4 b = B4[c]; float4 xa = xi4[c];
                a = __fmaf_rn(b.x, xa.x, a);
                a = __fmaf_rn(b.y, xa.y, a);
                a = __fmaf_rn(b.z, xa.z, a);
                a = __fmaf_rn(b.w, xa.w, a);
            }
            float den = __fadd_rn(__fmul_rn(ni, nj), 1e-8f);
            float thr = lv[TCH-1]*den;
            // conservative prefilter (margin >> fdiv rounding), exact recheck
            if (j != i && a > __fmaf_rn(fabsf(thr), -1e-6f, thr)){
                float s0 = __fdiv_rn(a, den);
                if (s0 > lv[TCH-1]){   // strict >: ties keep earlier idx (idx-asc rank)
                    lv[TCH-1] = s0; li[TCH-1] = j;
                    #pragma unroll
                    for (int r = TCH-1; r > 0; --r){
                        if (lv[r] > lv[r-1]){
                            float tv = lv[r]; lv[r] = lv[r-1]; lv[r-1] = tv;
                            int ti = li[r]; li[r] = li[r-1]; li[r-1] = ti;
                        }
                    }
                }
            }
        }
    }
    // transposed layout: [(split*TCH+r)*N + i] — coalesced store AND read
    #pragma unroll
    for (int r = 0; r < TCH; ++r){
        chV[(size_t)(split*TCH + r)*N + i] = lv[r];
        chI[(size_t)(split*TCH + r)*N + i] = li[r];
    }
}

// ---- exact top-16 of the candidate union; vectorized rescan of flagged chunks ----
__global__ __launch_bounds__(128) void k_sel16(const float* __restrict__ xf,
                                               const float* __restrict__ nrmf,
                                               const float* __restrict__ chV,
                                               const int* __restrict__ chI,
                                               int* __restrict__ topIdx,
                                               float* __restrict__ ewArr){
    int q = blockIdx.x*128 + threadIdx.x;

    float lv[16]; int li[16];
    #pragma unroll
    for (int r = 0; r < 16; ++r){ lv[r] = -3.0e38f; li[r] = INT_MAX; }

    // pass 1: provisional top-16 from all 32*TCH candidates (full comparator)
    for (int c = 0; c < NSPL; ++c){
        #pragma unroll
        for (int r = 0; r < TCH; ++r){
            float v = chV[(size_t)(c*TCH + r)*N + q];
            int  id = chI[(size_t)(c*TCH + r)*N + q];
            if (v > lv[15] || (v == lv[15] && id < li[15])){
                lv[15] = v; li[15] = id;
                #pragma unroll
                for (int k = 15; k > 0; --k){
                    if (lv[k] > lv[k-1] || (lv[k] == lv[k-1] && li[k] < li[k-1])){
                        float tv = lv[k]; lv[k] = lv[k-1]; lv[k-1] = tv;
                        int ti = li[k]; li[k] = li[k-1]; li[k-1] = ti;
                    }
                }
            }
        }
    }
    // flag chunks whose stored 6th ranks above the provisional 16th
    unsigned int flags = 0;
    for (int c = 0; c < NSPL; ++c){
        float v6 = chV[(size_t)(c*TCH + TCH-1)*N + q];
        int  i6 = chI[(size_t)(c*TCH + TCH-1)*N + q];
        if (v6 > lv[15] || (v6 == lv[15] && i6 < li[15])) flags |= (1u << c);
    }
    if (flags){
        // ~never taken (expected ~1-2 queries per run). Vectorized exact rescan.
        #pragma unroll
        for (int r = 0; r < 16; ++r){ lv[r] = -3.0e38f; li[r] = INT_MAX; }
        const float4* xq4 = (const float4*)(xf + (size_t)q*D);
        float4 xq[16];
        #pragma unroll
        for (int c = 0; c < 16; ++c) xq[c] = xq4[c];
        float ni = nrmf[q];
        for (int c = 0; c < NSPL; ++c){
            if ((flags >> c) & 1u){
                for (int j = c*JSPAN; j < c*JSPAN + JSPAN; ++j){
                    if (j == q) continue;
                    const float4* b4 = (const float4*)(xf + (size_t)j*D);
                    float a = 0.0f;
                    #pragma unroll
                    for (int k = 0; k < 16; ++k){
                        float4 b = b4[k]; float4 xa = xq[k];
                        a = __fmaf_rn(b.x, xa.x, a);
                        a = __fmaf_rn(b.y, xa.y, a);
                        a = __fmaf_rn(b.z, xa.z, a);
                        a = __fmaf_rn(b.w, xa.w, a);
                    }
                    float den = __fadd_rn(__fmul_rn(ni, nrmf[j]), 1e-8f);
                    float s0 = __fdiv_rn(a, den);
                    if (s0 > lv[15] || (s0 == lv[15] && j < li[15])){
                        lv[15] = s0; li[15] = j;
                        #pragma unroll
                        for (int k = 15; k > 0; --k){
                            if (lv[k] > lv[k-1] || (lv[k] == lv[k-1] && li[k] < li[k-1])){
                                float tv = lv[k]; lv[k] = lv[k-1]; lv[k-1] = tv;
                                int ti = li[k]; li[k] = li[k-1]; li[k-1] = ti;
                            }
                        }
                    }
                }
            } else {
                #pragma unroll
                for (int r = 0; r < TCH; ++r){
                    float v = chV[(size_t)(c*TCH + r)*N + q];
                    int  id = chI[(size_t)(c*TCH + r)*N + q];
                    if (v > lv[15] || (v == lv[15] && id < li[15])){
                        lv[15] = v; li[15] = id;
                        #pragma unroll
                        for (int k = 15; k > 0; --k){
                            if (lv[k] > lv[k-1] || (lv[k] == lv[k-1] && li[k] < li[k-1])){
                                float tv = lv[k]; lv[k] = lv[k-1]; lv[k-1] = tv;
                                int ti = li[k]; li[k] = li[k-1]; li[k-1] = ti;
                            }
                        }
                    }
                }
            }
        }
    }
    #pragma unroll
    for (int sel = 0; sel < KNB; ++sel){
        topIdx[q*KNB + sel] = li[sel];
        ewArr [q*KNB + sel] = (lv[sel] > 0.5f) ? lv[sel] : 0.0f;
    }
}

// ---------------- degree / dinv ----------------
__global__ void k_deg_init(double* __restrict__ degD){
    int j = blockIdx.x*blockDim.x + threadIdx.x;
    if (j < N) degD[j] = 2.0;
}
__global__ void k_deg_scatter(const int* __restrict__ topIdx, const float* __restrict__ ewArr,
                              double* __restrict__ degD){
    int e = blockIdx.x*blockDim.x + threadIdx.x;
    if (e < NE){
        float w = ewArr[e];
        if (w > 0.0f) atomicAdd(&degD[topIdx[e]], (double)w);
    }
}
__global__ void k_dinv(const double* __restrict__ degD, float* __restrict__ dinv){
    int j = blockIdx.x*blockDim.x + threadIdx.x;
    if (j < N) dinv[j] = (float)(1.0 / sqrt(degD[j]));
}

// ---------------- dense matmuls ----------------
__global__ void k_gemm1(const float* __restrict__ xf, const float* __restrict__ W1,
                        float* __restrict__ h1){
    int id = blockIdx.x*256 + threadIdx.x;
    int i = id >> 7; int f = id & (H-1);
    const float* xr = xf + i*D;
    float acc = 0.f;
    #pragma unroll
    for (int k = 0; k < D; ++k) acc += xr[k] * W1[k*H + f];
    h1[id] = acc;
}
__global__ void k_gemm2(const float* __restrict__ z1, const float* __restrict__ W2,
                        float* __restrict__ h2){
    int id = blockIdx.x*256 + threadIdx.x;
    int i = id >> 6; int f = id & (O-1);
    const float* zr = z1 + i*H;
    float acc = 0.f;
    #pragma unroll
    for (int k = 0; k < H; ++k) acc += zr[k] * W2[k*O + f];
    h2[id] = acc;
}
__global__ void k_proj(const float* __restrict__ z2, const float* __restrict__ Wp,
                       const float* __restrict__ bp, float* __restrict__ z3){
    int id = blockIdx.x*256 + threadIdx.x;
    int i = id >> 6; int f = id & (D-1);
    const float* zr = z2 + i*O;
    float acc = bp[f];
    #pragma unroll
    for (int k = 0; k < O; ++k) acc += zr[k] * Wp[k*D + f];
    z3[id] = acc;
}

// ---------------- GCN aggregation ----------------
template<int F>
__global__ void k_agg_init(const float* __restrict__ h, const float* __restrict__ dinv,
                           float* __restrict__ agg){
    int id = blockIdx.x*256 + threadIdx.x;
    int j = id / F;
    float dj = dinv[j];
    agg[id] = 2.f * dj * dj * h[id];
}
template<int F>
__global__ void k_agg_scat(const int* __restrict__ topIdx, const float* __restrict__ ewArr,
                           const float* __restrict__ dinv, const float* __restrict__ h,
                           float* __restrict__ agg){
    int e = blockIdx.x; int f = threadIdx.x;
    float w = ewArr[e];
    if (w == 0.f) return;
    int s = e >> 4;
    int dn = topIdx[e];
    float c = dinv[s] * w * dinv[dn];
    atomicAdd(&agg[dn*F + f], c * h[s*F + f]);
}

// ---------------- bias + relu + layernorm ----------------
__global__ void k_post128(const float* __restrict__ agg, const float* __restrict__ b,
                          const float* __restrict__ g, const float* __restrict__ be,
                          float* __restrict__ z){
    __shared__ double s2[2];
    __shared__ double s3[2];
    int i = blockIdx.x; int f = threadIdx.x;
    float v = agg[i*H + f] + b[f];
    v = v > 0.f ? v : 0.f;
    int wid = f >> 6;
    double d = (double)v;
    for (int off = 32; off > 0; off >>= 1) d += __shfl_xor(d, off);
    if ((f & 63) == 0) s2[wid] = d;
    __syncthreads();
    double mu = (s2[0] + s2[1]) * (1.0/128.0);
    double dv = (double)v - mu;
    double qq = dv * dv;
    for (int off = 32; off > 0; off >>= 1) qq += __shfl_xor(qq, off);
    if ((f & 63) == 0) s3[wid] = qq;
    __syncthreads();
    double var = (s3[0] + s3[1]) * (1.0/128.0);
    double rs = 1.0 / sqrt(var + 1e-5);
    z[i*H + f] = (float)(dv * rs * (double)g[f] + (double)be[f]);
}
__global__ void k_post64(const float* __restrict__ agg, const float* __restrict__ b,
                         const float* __restrict__ g, const float* __restrict__ be,
                         float* __restrict__ z){
    int i = blockIdx.x; int f = threadIdx.x;
    float v = agg[i*O + f] + b[f];
    v = v > 0.f ? v : 0.f;
    double d = (double)v;
    for (int off = 32; off > 0; off >>= 1) d += __shfl_xor(d, off);
    double mu = d * (1.0/64.0);
    double dv = (double)v - mu;
    double qq = dv * dv;
    for (int off = 32; off > 0; off >>= 1) qq += __shfl_xor(qq, off);
    double var = qq * (1.0/64.0);
    double rs = 1.0 / sqrt(var + 1e-5);
    z[i*O + f] = (float)(dv * rs * (double)g[f] + (double)be[f]);
}

// ---------------- fused output store + edges (flag-branched dtype) ----------------
__global__ void k_out(const float* __restrict__ z3, const int* __restrict__ topIdx,
                      const float* __restrict__ ewArr, void* __restrict__ outp,
                      const int* __restrict__ flag){
    int id = blockIdx.x*256 + threadIdx.x;
    if (id < OUT0){
        float v = z3[id];
        if (*flag) ((unsigned short*)outp)[id] = f2bf(v);
        else       ((float*)outp)[id] = v;
        return;
    }
    int e = id - OUT0;
    if (e >= ETOT) return;
    int s, dn; float w;
    if (e < NE){ s = e >> 4; dn = topIdx[e]; w = ewArr[e]; }
    else       { s = e - NE; dn = s;        w = 1.0f; }
    if (*flag){
        unsigned short* o = (unsigned short*)outp;
        o[OUT0 + e]          = f2bf((float)s);
        o[OUT0 + ETOT + e]   = f2bf((float)dn);
        o[OUT0 + 2*ETOT + e] = f2bf(w);
    } else {
        float* o = (float*)outp;
        o[OUT0 + e]          = (float)s;
        o[OUT0 + ETOT + e]   = (float)dn;
        o[OUT0 + 2*ETOT + e] = w;
    }
}

extern "C" void kernel_launch(void* const* d_in, const int* in_sizes, int n_in,
                              void* d_out, int out_size, void* d_ws, size_t ws_size,
                              hipStream_t stream){
    char* ws = (char*)d_ws;
    int*    flag   = (int*)   (ws + 0);
    float*  w1f    = (float*) (ws + 4096);
    float*  b1f    = (float*) (ws + 36864);
    float*  g1f    = (float*) (ws + 37376);
    float*  be1f   = (float*) (ws + 37888);
    float*  w2f    = (float*) (ws + 38400);
    float*  b2f    = (float*) (ws + 71168);
    float*  g2f    = (float*) (ws + 71424);
    float*  be2f   = (float*) (ws + 71680);
    float*  wpf    = (float*) (ws + 71936);
    float*  bpf    = (float*) (ws + 88320);
    float*  xf     = (float*) (ws + 98304);      // 2 MB          -> 2195456
    float*  nrmf   = (float*) (ws + 2195456);    // 32 KB         -> 2228224
    int*    topIdx = (int*)   (ws + 2260992);    // 512 KB        -> 2785280
    float*  ewArr  = (float*) (ws + 2785280);    // 512 KB        -> 3309568
    double* degD   = (double*)(ws + 3309568);    // 64 KB         -> 3375104
    float*  dinv   = (float*) (ws + 3375104);    // 32 KB         -> 3407872
    float*  h1     = (float*) (ws + 3407872);    // 4 MB          -> 7602176
    float*  agg1   = (float*) (ws + 7602176);    // 4 MB          -> 11796480
    float*  z1     = (float*) (ws + 11796480);   // 4 MB          -> 15990784
    float*  h2     = h1;
    float*  agg2   = agg1;
    float*  z2     = z1;
    float*  z3     = h1;

    // topk scratch overlaps h1/agg1/z1 (all dead until k_gemm1, which
    // launches after k_sel16 completes): chV 6.29 MB + chI 6.29 MB ends
    // exactly at 15990784 (= z1 end, the pre-existing high-water mark).
    float* chV = (float*)(ws + 3407872);
    int*   chI = (int*)  (ws + 9699328);

    k_probe<<<1, 256, 0, stream>>>((const unsigned short*)d_in[0], flag);
    k_cvt<<<(N*D+255)/256, 256, 0, stream>>>(d_in[0], xf,  N*D, flag);
    k_cvtp<<<(21120+255)/256, 256, 0, stream>>>(
        d_in[1], d_in[2], d_in[3], d_in[4], d_in[5],
        d_in[6], d_in[7], d_in[8], d_in[9], d_in[10],
        w1f, b1f, g1f, be1f, w2f, b2f, g2f, be2f, wpf, bpf, flag);

    k_prep<<<N/64, 64, 0, stream>>>(xf, nrmf);
    k_scan6<<<32*NSPL, 256, 0, stream>>>(xf, nrmf, chV, chI);
    k_sel16<<<N/128, 128, 0, stream>>>(xf, nrmf, chV, chI, topIdx, ewArr);

    k_deg_init<<<N/256, 256, 0, stream>>>(degD);
    k_deg_scatter<<<NE/256, 256, 0, stream>>>(topIdx, ewArr, degD);
    k_dinv<<<N/256, 256, 0, stream>>>(degD, dinv);

    k_gemm1<<<(N*H)/256, 256, 0, stream>>>(xf, w1f, h1);
    k_agg_init<H><<<(N*H)/256, 256, 0, stream>>>(h1, dinv, agg1);
    k_agg_scat<H><<<NE, H, 0, stream>>>(topIdx, ewArr, dinv, h1, agg1);
    k_post128<<<N, H, 0, stream>>>(agg1, b1f, g1f, be1f, z1);

    k_gemm2<<<(N*O)/256, 256, 0, stream>>>(z1, w2f, h2);
    k_agg_init<O><<<(N*O)/256, 256, 0, stream>>>(h2, dinv, agg2);
    k_agg_scat<O><<<NE, O, 0, stream>>>(topIdx, ewArr, dinv, h2, agg2);
    k_post64<<<N, O, 0, stream>>>(agg2, b2f, g2f, be2f, z2);

    k_proj<<<(N*D)/256, 256, 0, stream>>>(z2, wpf, bpf, z3);
    k_out<<<(OUT0+ETOT+255)/256, 256, 0, stream>>>(z3, topIdx, ewArr, d_out, flag);
}

// Round 11
// 839.610 us; speedup vs baseline: 2.6211x; 1.4491x over previous
//
#include <hip/hip_runtime.h>
#include <cstdint>
#include <climits>

#define N 8192
#define D 64
#define H 128
#define O 64
#define KNB 16
#define NE (N*KNB)        // 131072
#define ETOT (NE + N)     // 139264
#define OUT0 (N*D)        // 524288
#define NSPL 32           // j-splits (chunks)
#define JSPAN 256         // j's per chunk (N/NSPL)
#define JTILE 128         // j-rows staged in LDS per tile (32 KB)
#define TCH 6             // stored top-T per chunk (certificate depth)

__device__ __forceinline__ float bf2f(unsigned short u){
    union { unsigned int u; float f; } v; v.u = ((unsigned int)u) << 16; return v.f;
}
__device__ __forceinline__ unsigned short f2bf(float f){
    union { float f; unsigned int u; } v; v.f = f;
    unsigned int r = v.u + 0x7FFFu + ((v.u >> 16) & 1u);   // RNE
    return (unsigned short)(r >> 16);
}

#define PIN4(v) asm volatile("" : "+v"((v).x), "+v"((v).y), "+v"((v).z), "+v"((v).w))

// ---------------- dtype probe: 1=bf16 inputs, 0=fp32 inputs ----------------
__global__ void k_probe(const unsigned short* __restrict__ x, int* __restrict__ flag){
    __shared__ int cnt;
    if (threadIdx.x == 0) cnt = 0;
    __syncthreads();
    unsigned short u = x[2*threadIdx.x];
    int e = (u >> 7) & 0xFF;
    int ok = (u == 0) || (e >= 0x60 && e <= 0x85);
    unsigned long long m = __ballot(ok);
    if ((threadIdx.x & 63) == 0) atomicAdd(&cnt, __popcll(m));
    __syncthreads();
    if (threadIdx.x == 0) *flag = (cnt >= 128) ? 1 : 0;
}

// ---------------- x convert -> fp32 ----------------
__global__ void k_cvt(const void* __restrict__ src, float* __restrict__ dst,
                      int n, const int* __restrict__ flag){
    int i = blockIdx.x*256 + threadIdx.x;
    if (i >= n) return;
    if (*flag) dst[i] = bf2f(((const unsigned short*)src)[i]);
    else       dst[i] = ((const float*)src)[i];
}

// ---------------- fused param convert (10 tensors, one launch) ----------------
__global__ void k_cvtp(const void* s1, const void* s2, const void* s3, const void* s4,
                       const void* s5, const void* s6, const void* s7, const void* s8,
                       const void* s9, const void* s10,
                       float* d1, float* d2, float* d3, float* d4, float* d5,
                       float* d6, float* d7, float* d8, float* d9, float* d10,
                       const int* __restrict__ flag){
    int id = blockIdx.x*256 + threadIdx.x;
    const void* s; float* d; int off;
    if      (id <  8192){ s = s1;  d = d1;  off = id; }
    else if (id <  8320){ s = s2;  d = d2;  off = id - 8192; }
    else if (id <  8448){ s = s3;  d = d3;  off = id - 8320; }
    else if (id <  8576){ s = s4;  d = d4;  off = id - 8448; }
    else if (id < 16768){ s = s5;  d = d5;  off = id - 8576; }
    else if (id < 16832){ s = s6;  d = d6;  off = id - 16768; }
    else if (id < 16896){ s = s7;  d = d7;  off = id - 16832; }
    else if (id < 16960){ s = s8;  d = d8;  off = id - 16896; }
    else if (id < 21056){ s = s9;  d = d9;  off = id - 16960; }
    else if (id < 21120){ s = s10; d = d10; off = id - 21056; }
    else return;
    if (*flag) d[off] = bf2f(((const unsigned short*)s)[off]);
    else       d[off] = ((const float*)s)[off];
}

// ---------------- row norms: EXACT numpy fp32 pairwise semantics ----------------
__global__ void k_prep(const float* __restrict__ xf, float* __restrict__ nrmf){
    int i = blockIdx.x*64 + threadIdx.x;
    const float* xr = xf + i*D;
    float r[8];
    #pragma unroll
    for (int q = 0; q < 8; ++q) r[q] = __fmul_rn(xr[q], xr[q]);
    #pragma unroll
    for (int b = 8; b < 64; b += 8)
        #pragma unroll
        for (int q = 0; q < 8; ++q)
            r[q] = __fadd_rn(r[q], __fmul_rn(xr[b+q], xr[b+q]));
    float s = __fadd_rn(__fadd_rn(__fadd_rn(r[0],r[1]), __fadd_rn(r[2],r[3])),
                        __fadd_rn(__fadd_rn(r[4],r[5]), __fadd_rn(r[6],r[7])));
    nrmf[i] = __fsqrt_rn(s);
}

// =====================================================================
// Single-scan exact top-k with per-chunk top-6 certificate.
// k_scan6: top-6 (value,idx) per 256-j chunk per query (LDS-broadcast
// j-rows, round-8-verified). k_sel16: ONE WAVE PER QUERY (round-10
// post-mortem: thread-per-query had 128 waves total on 1024 SIMDs,
// occupancy 0.78%, latency-bound at 920us). Lanes hold 3 candidates
// each as order-preserving 64-bit keys; top-16 = 16 wave-max shfl
// reductions. Keys: [float->uint monotone map | ~idx] so key_a>key_b
// <=> (value desc, idx asc) — exactly jax.lax.top_k's comparator; keys
// unique (distinct j). CERTIFICATE: every element NOT stored for chunk c
// ranks strictly below c's stored 6th; if no chunk's 6th outranks the
// 16th selected, the union top-16 is the true top-16. Fallback (exact
// vectorized rescan of flagged chunks) is wave-uniform and runs on
// lane 0 — P(fire) ~ 1.7e-4/query, and even if 100x that, firing waves
// run concurrently with the rest at high occupancy.
// Sim chain (bitwise-stable, operand-source independent):
//   a = fma-chain k=0..63; den = fadd(fmul(ni,nj),1e-8); s = fdiv(a,den).
// =====================================================================

__global__ __launch_bounds__(256, 2) void k_scan6(const float* __restrict__ xf,
                                                  const float* __restrict__ nrmf,
                                                  float* __restrict__ chV,
                                                  int* __restrict__ chI){
    __shared__ float sB[JTILE*64];   // 32 KB j-row tile
    __shared__ float sN[JTILE];

    int tid = threadIdx.x;
    int grp = blockIdx.x & 31;        // 32 query groups of 256
    int split = blockIdx.x >> 5;      // 32 chunks
    int i = grp*256 + tid;
    int jbase = split*JSPAN;

    const float4* xip = (const float4*)(xf + (size_t)i*D);
    float4 xi4[16];
    #pragma unroll
    for (int c = 0; c < 16; ++c) xi4[c] = xip[c];
    #pragma unroll
    for (int c = 0; c < 16; ++c) PIN4(xi4[c]);
    float ni = nrmf[i];

    float lv[TCH]; int li[TCH];
    #pragma unroll
    for (int r = 0; r < TCH; ++r){ lv[r] = -3.0e38f; li[r] = INT_MAX; }

    for (int t = 0; t < JSPAN/JTILE; ++t){
        int jt = jbase + t*JTILE;
        __syncthreads();   // previous tile fully consumed
        #pragma unroll
        for (int u = 0; u < (JTILE*16)/256; ++u){
            int idx = u*256 + tid;
            ((float4*)sB)[idx] = ((const float4*)xf)[(size_t)jt*16 + idx];
        }
        if (tid < JTILE) sN[tid] = nrmf[jt + tid];
        __syncthreads();

        for (int jj = 0; jj < JTILE; ++jj){
            int j = jt + jj;
            const float4* B4 = (const float4*)(sB + jj*64);   // uniform -> broadcast
            float nj = sN[jj];
            float a = 0.0f;
            #pragma unroll
            for (int c = 0; c < 16; ++c){
                float4 b = B4[c]; float4 xa = xi4[c];
                a = __fmaf_rn(b.x, xa.x, a);
                a = __fmaf_rn(b.y, xa.y, a);
                a = __fmaf_rn(b.z, xa.z, a);
                a = __fmaf_rn(b.w, xa.w, a);
            }
            float den = __fadd_rn(__fmul_rn(ni, nj), 1e-8f);
            float thr = lv[TCH-1]*den;
            // conservative prefilter (margin >> fdiv rounding), exact recheck
            if (j != i && a > __fmaf_rn(fabsf(thr), -1e-6f, thr)){
                float s0 = __fdiv_rn(a, den);
                if (s0 > lv[TCH-1]){   // strict >: ties keep earlier idx (idx-asc rank)
                    lv[TCH-1] = s0; li[TCH-1] = j;
                    #pragma unroll
                    for (int r = TCH-1; r > 0; --r){
                        if (lv[r] > lv[r-1]){
                            float tv = lv[r]; lv[r] = lv[r-1]; lv[r-1] = tv;
                            int ti = li[r]; li[r] = li[r-1]; li[r-1] = ti;
                        }
                    }
                }
            }
        }
    }
    // transposed layout: [(split*TCH+r)*N + i] — coalesced store
    #pragma unroll
    for (int r = 0; r < TCH; ++r){
        chV[(size_t)(split*TCH + r)*N + i] = lv[r];
        chI[(size_t)(split*TCH + r)*N + i] = li[r];
    }
}

// ---- wave-per-query exact top-16 of the 192-candidate union ----
__global__ __launch_bounds__(256, 2) void k_sel16(const float* __restrict__ xf,
                                                  const float* __restrict__ nrmf,
                                                  const float* __restrict__ chV,
                                                  const int* __restrict__ chI,
                                                  int* __restrict__ topIdx,
                                                  float* __restrict__ ewArr){
    int q = (blockIdx.x*256 + threadIdx.x) >> 6;   // one wave per query
    int lane = threadIdx.x & 63;

    // load 3 slots per lane as order-preserving 64-bit keys
    unsigned long long okey[3], key[3];
    #pragma unroll
    for (int s = 0; s < 3; ++s){
        int slot = lane + 64*s;
        float v = chV[(size_t)slot*N + q];
        int  id = chI[(size_t)slot*N + q];
        unsigned int u = __float_as_uint(v);
        if ((u & 0x7FFFFFFFu) == 0u) u = 0u;              // -0 -> +0 (== in fp)
        u = (u & 0x80000000u) ? ~u : (u | 0x80000000u);   // monotone float map
        unsigned long long kk = ((unsigned long long)u << 32)
                              | (unsigned long long)(unsigned int)(~(unsigned int)id);
        okey[s] = kk; key[s] = kk;   // keys unique: idx distinct per query
    }

    float wv[16]; int widx[16];
    unsigned long long k16 = 0ull;
    #pragma unroll
    for (int sel = 0; sel < KNB; ++sel){
        unsigned long long m = key[0] > key[1] ? key[0] : key[1];
        if (key[2] > m) m = key[2];
        #pragma unroll
        for (int off = 32; off > 0; off >>= 1){
            unsigned long long o = __shfl_xor(m, off);
            if (o > m) m = o;
        }
        if      (key[0] == m) key[0] = 0ull;   // owner removes (0 < any real key)
        else if (key[1] == m) key[1] = 0ull;
        else if (key[2] == m) key[2] = 0ull;
        unsigned int um = (unsigned int)(m >> 32);
        unsigned int ou = (um & 0x80000000u) ? (um & 0x7FFFFFFFu) : ~um;
        wv[sel]  = __uint_as_float(ou);
        widx[sel] = (int)~((unsigned int)m);
        k16 = m;
    }

    // certificate: does any chunk's stored 6th outrank the 16th selected?
    bool fl = false;
    #pragma unroll
    for (int s = 0; s < 3; ++s){
        int slot = lane + 64*s;
        if ((slot % TCH) == TCH-1 && okey[s] > k16) fl = true;
    }
    if (__ballot(fl) == 0ull){
        if (lane == 0){
            #pragma unroll
            for (int sel = 0; sel < KNB; ++sel){
                topIdx[q*KNB + sel] = widx[sel];
                ewArr [q*KNB + sel] = (wv[sel] > 0.5f) ? wv[sel] : 0.0f;
            }
        }
        return;
    }
    if (lane != 0) return;

    // ---- rare exact fallback (serial on lane 0, vectorized chain) ----
    float lv[16]; int li[16];
    #pragma unroll
    for (int r = 0; r < 16; ++r){ lv[r] = -3.0e38f; li[r] = INT_MAX; }
    unsigned int flags = 0;
    for (int c = 0; c < NSPL; ++c){
        float v6 = chV[(size_t)(c*TCH + TCH-1)*N + q];
        int  i6 = chI[(size_t)(c*TCH + TCH-1)*N + q];
        if (v6 > wv[15] || (v6 == wv[15] && i6 < widx[15])) flags |= (1u << c);
    }
    const float4* xq4 = (const float4*)(xf + (size_t)q*D);
    float4 xq[16];
    #pragma unroll
    for (int c = 0; c < 16; ++c) xq[c] = xq4[c];
    float ni = nrmf[q];
    for (int c = 0; c < NSPL; ++c){
        if ((flags >> c) & 1u){
            for (int j = c*JSPAN; j < c*JSPAN + JSPAN; ++j){
                if (j == q) continue;
                const float4* b4 = (const float4*)(xf + (size_t)j*D);
                float a = 0.0f;
                #pragma unroll
                for (int k = 0; k < 16; ++k){
                    float4 b = b4[k]; float4 xa = xq[k];
                    a = __fmaf_rn(b.x, xa.x, a);
                    a = __fmaf_rn(b.y, xa.y, a);
                    a = __fmaf_rn(b.z, xa.z, a);
                    a = __fmaf_rn(b.w, xa.w, a);
                }
                float den = __fadd_rn(__fmul_rn(ni, nrmf[j]), 1e-8f);
                float s0 = __fdiv_rn(a, den);
                if (s0 > lv[15] || (s0 == lv[15] && j < li[15])){
                    lv[15] = s0; li[15] = j;
                    #pragma unroll
                    for (int k = 15; k > 0; --k){
                        if (lv[k] > lv[k-1] || (lv[k] == lv[k-1] && li[k] < li[k-1])){
                            float tv = lv[k]; lv[k] = lv[k-1]; lv[k-1] = tv;
                            int ti = li[k]; li[k] = li[k-1]; li[k-1] = ti;
                        }
                    }
                }
            }
        } else {
            #pragma unroll
            for (int r = 0; r < TCH; ++r){
                float v = chV[(size_t)(c*TCH + r)*N + q];
                int  id = chI[(size_t)(c*TCH + r)*N + q];
                if (v > lv[15] || (v == lv[15] && id < li[15])){
                    lv[15] = v; li[15] = id;
                    #pragma unroll
                    for (int k = 15; k > 0; --k){
                        if (lv[k] > lv[k-1] || (lv[k] == lv[k-1] && li[k] < li[k-1])){
                            float tv = lv[k]; lv[k] = lv[k-1]; lv[k-1] = tv;
                            int ti = li[k]; li[k] = li[k-1]; li[k-1] = ti;
                        }
                    }
                }
            }
        }
    }
    #pragma unroll
    for (int sel = 0; sel < KNB; ++sel){
        topIdx[q*KNB + sel] = li[sel];
        ewArr [q*KNB + sel] = (lv[sel] > 0.5f) ? lv[sel] : 0.0f;
    }
}

// ---------------- degree / dinv ----------------
__global__ void k_deg_init(double* __restrict__ degD){
    int j = blockIdx.x*blockDim.x + threadIdx.x;
    if (j < N) degD[j] = 2.0;
}
__global__ void k_deg_scatter(const int* __restrict__ topIdx, const float* __restrict__ ewArr,
                              double* __restrict__ degD){
    int e = blockIdx.x*blockDim.x + threadIdx.x;
    if (e < NE){
        float w = ewArr[e];
        if (w > 0.0f) atomicAdd(&degD[topIdx[e]], (double)w);
    }
}
__global__ void k_dinv(const double* __restrict__ degD, float* __restrict__ dinv){
    int j = blockIdx.x*blockDim.x + threadIdx.x;
    if (j < N) dinv[j] = (float)(1.0 / sqrt(degD[j]));
}

// ---------------- dense matmuls ----------------
__global__ void k_gemm1(const float* __restrict__ xf, const float* __restrict__ W1,
                        float* __restrict__ h1){
    int id = blockIdx.x*256 + threadIdx.x;
    int i = id >> 7; int f = id & (H-1);
    const float* xr = xf + i*D;
    float acc = 0.f;
    #pragma unroll
    for (int k = 0; k < D; ++k) acc += xr[k] * W1[k*H + f];
    h1[id] = acc;
}
__global__ void k_gemm2(const float* __restrict__ z1, const float* __restrict__ W2,
                        float* __restrict__ h2){
    int id = blockIdx.x*256 + threadIdx.x;
    int i = id >> 6; int f = id & (O-1);
    const float* zr = z1 + i*H;
    float acc = 0.f;
    #pragma unroll
    for (int k = 0; k < H; ++k) acc += zr[k] * W2[k*O + f];
    h2[id] = acc;
}
__global__ void k_proj(const float* __restrict__ z2, const float* __restrict__ Wp,
                       const float* __restrict__ bp, float* __restrict__ z3){
    int id = blockIdx.x*256 + threadIdx.x;
    int i = id >> 6; int f = id & (D-1);
    const float* zr = z2 + i*O;
    float acc = bp[f];
    #pragma unroll
    for (int k = 0; k < O; ++k) acc += zr[k] * Wp[k*D + f];
    z3[id] = acc;
}

// ---------------- GCN aggregation ----------------
template<int F>
__global__ void k_agg_init(const float* __restrict__ h, const float* __restrict__ dinv,
                           float* __restrict__ agg){
    int id = blockIdx.x*256 + threadIdx.x;
    int j = id / F;
    float dj = dinv[j];
    agg[id] = 2.f * dj * dj * h[id];
}
template<int F>
__global__ void k_agg_scat(const int* __restrict__ topIdx, const float* __restrict__ ewArr,
                           const float* __restrict__ dinv, const float* __restrict__ h,
                           float* __restrict__ agg){
    int e = blockIdx.x; int f = threadIdx.x;
    float w = ewArr[e];
    if (w == 0.f) return;
    int s = e >> 4;
    int dn = topIdx[e];
    float c = dinv[s] * w * dinv[dn];
    atomicAdd(&agg[dn*F + f], c * h[s*F + f]);
}

// ---------------- bias + relu + layernorm ----------------
__global__ void k_post128(const float* __restrict__ agg, const float* __restrict__ b,
                          const float* __restrict__ g, const float* __restrict__ be,
                          float* __restrict__ z){
    __shared__ double s2[2];
    __shared__ double s3[2];
    int i = blockIdx.x; int f = threadIdx.x;
    float v = agg[i*H + f] + b[f];
    v = v > 0.f ? v : 0.f;
    int wid = f >> 6;
    double d = (double)v;
    for (int off = 32; off > 0; off >>= 1) d += __shfl_xor(d, off);
    if ((f & 63) == 0) s2[wid] = d;
    __syncthreads();
    double mu = (s2[0] + s2[1]) * (1.0/128.0);
    double dv = (double)v - mu;
    double qq = dv * dv;
    for (int off = 32; off > 0; off >>= 1) qq += __shfl_xor(qq, off);
    if ((f & 63) == 0) s3[wid] = qq;
    __syncthreads();
    double var = (s3[0] + s3[1]) * (1.0/128.0);
    double rs = 1.0 / sqrt(var + 1e-5);
    z[i*H + f] = (float)(dv * rs * (double)g[f] + (double)be[f]);
}
__global__ void k_post64(const float* __restrict__ agg, const float* __restrict__ b,
                         const float* __restrict__ g, const float* __restrict__ be,
                         float* __restrict__ z){
    int i = blockIdx.x; int f = threadIdx.x;
    float v = agg[i*O + f] + b[f];
    v = v > 0.f ? v : 0.f;
    double d = (double)v;
    for (int off = 32; off > 0; off >>= 1) d += __shfl_xor(d, off);
    double mu = d * (1.0/64.0);
    double dv = (double)v - mu;
    double qq = dv * dv;
    for (int off = 32; off > 0; off >>= 1) qq += __shfl_xor(qq, off);
    double var = qq * (1.0/64.0);
    double rs = 1.0 / sqrt(var + 1e-5);
    z[i*O + f] = (float)(dv * rs * (double)g[f] + (double)be[f]);
}

// ---------------- fused output store + edges (flag-branched dtype) ----------------
__global__ void k_out(const float* __restrict__ z3, const int* __restrict__ topIdx,
                      const float* __restrict__ ewArr, void* __restrict__ outp,
                      const int* __restrict__ flag){
    int id = blockIdx.x*256 + threadIdx.x;
    if (id < OUT0){
        float v = z3[id];
        if (*flag) ((unsigned short*)outp)[id] = f2bf(v);
        else       ((float*)outp)[id] = v;
        return;
    }
    int e = id - OUT0;
    if (e >= ETOT) return;
    int s, dn; float w;
    if (e < NE){ s = e >> 4; dn = topIdx[e]; w = ewArr[e]; }
    else       { s = e - NE; dn = s;        w = 1.0f; }
    if (*flag){
        unsigned short* o = (unsigned short*)outp;
        o[OUT0 + e]          = f2bf((float)s);
        o[OUT0 + ETOT + e]   = f2bf((float)dn);
        o[OUT0 + 2*ETOT + e] = f2bf(w);
    } else {
        float* o = (float*)outp;
        o[OUT0 + e]          = (float)s;
        o[OUT0 + ETOT + e]   = (float)dn;
        o[OUT0 + 2*ETOT + e] = w;
    }
}

extern "C" void kernel_launch(void* const* d_in, const int* in_sizes, int n_in,
                              void* d_out, int out_size, void* d_ws, size_t ws_size,
                              hipStream_t stream){
    char* ws = (char*)d_ws;
    int*    flag   = (int*)   (ws + 0);
    float*  w1f    = (float*) (ws + 4096);
    float*  b1f    = (float*) (ws + 36864);
    float*  g1f    = (float*) (ws + 37376);
    float*  be1f   = (float*) (ws + 37888);
    float*  w2f    = (float*) (ws + 38400);
    float*  b2f    = (float*) (ws + 71168);
    float*  g2f    = (float*) (ws + 71424);
    float*  be2f   = (float*) (ws + 71680);
    float*  wpf    = (float*) (ws + 71936);
    float*  bpf    = (float*) (ws + 88320);
    float*  xf     = (float*) (ws + 98304);      // 2 MB          -> 2195456
    float*  nrmf   = (float*) (ws + 2195456);    // 32 KB         -> 2228224
    int*    topIdx = (int*)   (ws + 2260992);    // 512 KB        -> 2785280
    float*  ewArr  = (float*) (ws + 2785280);    // 512 KB        -> 3309568
    double* degD   = (double*)(ws + 3309568);    // 64 KB         -> 3375104
    float*  dinv   = (float*) (ws + 3375104);    // 32 KB         -> 3407872
    float*  h1     = (float*) (ws + 3407872);    // 4 MB          -> 7602176
    float*  agg1   = (float*) (ws + 7602176);    // 4 MB          -> 11796480
    float*  z1     = (float*) (ws + 11796480);   // 4 MB          -> 15990784
    float*  h2     = h1;
    float*  agg2   = agg1;
    float*  z2     = z1;
    float*  z3     = h1;

    // topk scratch overlaps h1/agg1/z1 (all dead until k_gemm1, which
    // launches after k_sel16 completes): chV 6.29 MB + chI 6.29 MB ends
    // exactly at 15990784 (= z1 end, the pre-existing high-water mark).
    float* chV = (float*)(ws + 3407872);
    int*   chI = (int*)  (ws + 9699328);

    k_probe<<<1, 256, 0, stream>>>((const unsigned short*)d_in[0], flag);
    k_cvt<<<(N*D+255)/256, 256, 0, stream>>>(d_in[0], xf,  N*D, flag);
    k_cvtp<<<(21120+255)/256, 256, 0, stream>>>(
        d_in[1], d_in[2], d_in[3], d_in[4], d_in[5],
        d_in[6], d_in[7], d_in[8], d_in[9], d_in[10],
        w1f, b1f, g1f, be1f, w2f, b2f, g2f, be2f, wpf, bpf, flag);

    k_prep<<<N/64, 64, 0, stream>>>(xf, nrmf);
    k_scan6<<<32*NSPL, 256, 0, stream>>>(xf, nrmf, chV, chI);
    k_sel16<<<(N*64)/256, 256, 0, stream>>>(xf, nrmf, chV, chI, topIdx, ewArr);

    k_deg_init<<<N/256, 256, 0, stream>>>(degD);
    k_deg_scatter<<<NE/256, 256, 0, stream>>>(topIdx, ewArr, degD);
    k_dinv<<<N/256, 256, 0, stream>>>(degD, dinv);

    k_gemm1<<<(N*H)/256, 256, 0, stream>>>(xf, w1f, h1);
    k_agg_init<H><<<(N*H)/256, 256, 0, stream>>>(h1, dinv, agg1);
    k_agg_scat<H><<<NE, H, 0, stream>>>(topIdx, ewArr, dinv, h1, agg1);
    k_post128<<<N, H, 0, stream>>>(agg1, b1f, g1f, be1f, z1);

    k_gemm2<<<(N*O)/256, 256, 0, stream>>>(z1, w2f, h2);
    k_agg_init<O><<<(N*O)/256, 256, 0, stream>>>(h2, dinv, agg2);
    k_agg_scat<O><<<NE, O, 0, stream>>>(topIdx, ewArr, dinv, h2, agg2);
    k_post64<<<N, O, 0, stream>>>(agg2, b2f, g2f, be2f, z2);

    k_proj<<<(N*D)/256, 256, 0, stream>>>(z2, wpf, bpf, z3);
    k_out<<<(OUT0+ETOT+255)/256, 256, 0, stream>>>(z3, topIdx, ewArr, d_out, flag);
}

// Round 15
// 455.281 us; speedup vs baseline: 4.8337x; 1.8442x over previous
//
#include <hip/hip_runtime.h>
#include <cstdint>
#include <climits>

#define N 8192
#define D 64
#define H 128
#define O 64
#define KNB 16
#define NE (N*KNB)        // 131072
#define ETOT (NE + N)     // 139264
#define OUT0 (N*D)        // 524288
#define NSPL 32           // j-splits (chunks)
#define JSPAN 256         // j's per chunk (N/NSPL)
#define JTILE 128         // j-rows staged in LDS per tile (32 KB)
#define TCH 8             // stored top-T per chunk (certificate depth)

__device__ __forceinline__ float bf2f(unsigned short u){
    union { unsigned int u; float f; } v; v.u = ((unsigned int)u) << 16; return v.f;
}
__device__ __forceinline__ unsigned short f2bf(float f){
    union { float f; unsigned int u; } v; v.f = f;
    unsigned int r = v.u + 0x7FFFu + ((v.u >> 16) & 1u);   // RNE
    return (unsigned short)(r >> 16);
}

#define PIN4(v) asm volatile("" : "+v"((v).x), "+v"((v).y), "+v"((v).z), "+v"((v).w))

// ---------------- dtype probe: 1=bf16 inputs, 0=fp32 inputs ----------------
__global__ void k_probe(const unsigned short* __restrict__ x, int* __restrict__ flag){
    __shared__ int cnt;
    if (threadIdx.x == 0) cnt = 0;
    __syncthreads();
    unsigned short u = x[2*threadIdx.x];
    int e = (u >> 7) & 0xFF;
    int ok = (u == 0) || (e >= 0x60 && e <= 0x85);
    unsigned long long m = __ballot(ok);
    if ((threadIdx.x & 63) == 0) atomicAdd(&cnt, __popcll(m));
    __syncthreads();
    if (threadIdx.x == 0) *flag = (cnt >= 128) ? 1 : 0;
}

// ---------------- x convert -> fp32 ----------------
__global__ void k_cvt(const void* __restrict__ src, float* __restrict__ dst,
                      int n, const int* __restrict__ flag){
    int i = blockIdx.x*256 + threadIdx.x;
    if (i >= n) return;
    if (*flag) dst[i] = bf2f(((const unsigned short*)src)[i]);
    else       dst[i] = ((const float*)src)[i];
}

// ---------------- fused param convert (10 tensors, one launch) ----------------
__global__ void k_cvtp(const void* s1, const void* s2, const void* s3, const void* s4,
                       const void* s5, const void* s6, const void* s7, const void* s8,
                       const void* s9, const void* s10,
                       float* d1, float* d2, float* d3, float* d4, float* d5,
                       float* d6, float* d7, float* d8, float* d9, float* d10,
                       const int* __restrict__ flag){
    int id = blockIdx.x*256 + threadIdx.x;
    const void* s; float* d; int off;
    if      (id <  8192){ s = s1;  d = d1;  off = id; }
    else if (id <  8320){ s = s2;  d = d2;  off = id - 8192; }
    else if (id <  8448){ s = s3;  d = d3;  off = id - 8320; }
    else if (id <  8576){ s = s4;  d = d4;  off = id - 8448; }
    else if (id < 16768){ s = s5;  d = d5;  off = id - 8576; }
    else if (id < 16832){ s = s6;  d = d6;  off = id - 16768; }
    else if (id < 16896){ s = s7;  d = d7;  off = id - 16832; }
    else if (id < 16960){ s = s8;  d = d8;  off = id - 16896; }
    else if (id < 21056){ s = s9;  d = d9;  off = id - 16960; }
    else if (id < 21120){ s = s10; d = d10; off = id - 21056; }
    else return;
    if (*flag) d[off] = bf2f(((const unsigned short*)s)[off]);
    else       d[off] = ((const float*)s)[off];
}

// ---------------- row norms: EXACT numpy fp32 pairwise semantics ----------------
__global__ void k_prep(const float* __restrict__ xf, float* __restrict__ nrmf){
    int i = blockIdx.x*64 + threadIdx.x;
    const float* xr = xf + i*D;
    float r[8];
    #pragma unroll
    for (int q = 0; q < 8; ++q) r[q] = __fmul_rn(xr[q], xr[q]);
    #pragma unroll
    for (int b = 8; b < 64; b += 8)
        #pragma unroll
        for (int q = 0; q < 8; ++q)
            r[q] = __fadd_rn(r[q], __fmul_rn(xr[b+q], xr[b+q]));
    float s = __fadd_rn(__fadd_rn(__fadd_rn(r[0],r[1]), __fadd_rn(r[2],r[3])),
                        __fadd_rn(__fadd_rn(r[4],r[5]), __fadd_rn(r[6],r[7])));
    nrmf[i] = __fsqrt_rn(s);
}

// =====================================================================
// Single-scan exact top-k with per-chunk top-8 certificate.
// k_scan8: top-8 (value,idx) per 256-j chunk per query (LDS-broadcast
// j-rows, round-8-verified). k_sel16: one wave per query; 16 wave-max
// key reductions over the 256 stored candidates (round-11-proven code
// shapes; 4 slots/lane). CERTIFICATE: every element NOT stored for
// chunk c ranks strictly below c's stored 8th; if no chunk's 8th
// outranks the provisional 16th, the union top-16 is the true top-16.
// TCH=8 => P(fire) = 32*C(16,8)/32^8 ~ 3.7e-7/query (~0.003 per RUN):
// the serial lane-0 fallback (round-11 code, compiled+passed) remains
// as an unconditional correctness net but ~never executes — this kills
// the 450us serial-fallback tail measured in round 11 WITHOUT new
// compiler-hostile code (rounds 12/13/14: three wave-parallel fallback
// variants all ICE'd clang-22; the trigger shape is a non-unrolled loop
// around the ull-shfl reduction — avoided entirely here).
// Sim chain (bitwise-stable, operand-source independent):
//   a = fma-chain k=0..63; den = fadd(fmul(ni,nj),1e-8); s = fdiv(a,den).
// =====================================================================

__global__ __launch_bounds__(256, 2) void k_scan8(const float* __restrict__ xf,
                                                  const float* __restrict__ nrmf,
                                                  float* __restrict__ chV,
                                                  int* __restrict__ chI){
    __shared__ float sB[JTILE*64];   // 32 KB j-row tile
    __shared__ float sN[JTILE];

    int tid = threadIdx.x;
    int grp = blockIdx.x & 31;        // 32 query groups of 256
    int split = blockIdx.x >> 5;      // 32 chunks
    int i = grp*256 + tid;
    int jbase = split*JSPAN;

    const float4* xip = (const float4*)(xf + (size_t)i*D);
    float4 xi4[16];
    #pragma unroll
    for (int c = 0; c < 16; ++c) xi4[c] = xip[c];
    #pragma unroll
    for (int c = 0; c < 16; ++c) PIN4(xi4[c]);
    float ni = nrmf[i];

    float lv[TCH]; int li[TCH];
    #pragma unroll
    for (int r = 0; r < TCH; ++r){ lv[r] = -3.0e38f; li[r] = INT_MAX; }

    for (int t = 0; t < JSPAN/JTILE; ++t){
        int jt = jbase + t*JTILE;
        __syncthreads();   // previous tile fully consumed
        #pragma unroll
        for (int u = 0; u < (JTILE*16)/256; ++u){
            int idx = u*256 + tid;
            ((float4*)sB)[idx] = ((const float4*)xf)[(size_t)jt*16 + idx];
        }
        if (tid < JTILE) sN[tid] = nrmf[jt + tid];
        __syncthreads();

        for (int jj = 0; jj < JTILE; ++jj){
            int j = jt + jj;
            const float4* B4 = (const float4*)(sB + jj*64);   // uniform -> broadcast
            float nj = sN[jj];
            float a = 0.0f;
            #pragma unroll
            for (int c = 0; c < 16; ++c){
                float4 b = B4[c]; float4 xa = xi4[c];
                a = __fmaf_rn(b.x, xa.x, a);
                a = __fmaf_rn(b.y, xa.y, a);
                a = __fmaf_rn(b.z, xa.z, a);
                a = __fmaf_rn(b.w, xa.w, a);
            }
            float den = __fadd_rn(__fmul_rn(ni, nj), 1e-8f);
            float thr = lv[TCH-1]*den;
            // conservative prefilter (margin >> fdiv rounding), exact recheck
            if (j != i && a > __fmaf_rn(fabsf(thr), -1e-6f, thr)){
                float s0 = __fdiv_rn(a, den);
                if (s0 > lv[TCH-1]){   // strict >: ties keep earlier idx (idx-asc rank)
                    lv[TCH-1] = s0; li[TCH-1] = j;
                    #pragma unroll
                    for (int r = TCH-1; r > 0; --r){
                        if (lv[r] > lv[r-1]){
                            float tv = lv[r]; lv[r] = lv[r-1]; lv[r-1] = tv;
                            int ti = li[r]; li[r] = li[r-1]; li[r-1] = ti;
                        }
                    }
                }
            }
        }
    }
    // transposed layout: [(split*TCH+r)*N + i] — coalesced store
    #pragma unroll
    for (int r = 0; r < TCH; ++r){
        chV[(size_t)(split*TCH + r)*N + i] = lv[r];
        chI[(size_t)(split*TCH + r)*N + i] = li[r];
    }
}

// ---- wave-per-query exact top-16 of the 256-candidate union ----
__global__ __launch_bounds__(256, 2) void k_sel16(const float* __restrict__ xf,
                                                  const float* __restrict__ nrmf,
                                                  const float* __restrict__ chV,
                                                  const int* __restrict__ chI,
                                                  int* __restrict__ topIdx,
                                                  float* __restrict__ ewArr){
    int q = (blockIdx.x*256 + threadIdx.x) >> 6;   // one wave per query
    int lane = threadIdx.x & 63;

    // load 4 slots per lane as order-preserving 64-bit keys
    unsigned long long okey[4], key[4];
    #pragma unroll
    for (int s = 0; s < 4; ++s){
        int slot = lane + 64*s;
        float v = chV[(size_t)slot*N + q];
        int  id = chI[(size_t)slot*N + q];
        unsigned int u = __float_as_uint(v);
        if ((u & 0x7FFFFFFFu) == 0u) u = 0u;              // -0 -> +0
        u = (u & 0x80000000u) ? ~u : (u | 0x80000000u);   // monotone float map
        unsigned long long kk = ((unsigned long long)u << 32)
                              | (unsigned long long)(unsigned int)(~(unsigned int)id);
        okey[s] = kk; key[s] = kk;
    }

    float wv[16]; int widx[16];
    unsigned long long k16 = 0ull;
    #pragma unroll
    for (int sel = 0; sel < KNB; ++sel){
        unsigned long long m = key[0] > key[1] ? key[0] : key[1];
        if (key[2] > m) m = key[2];
        if (key[3] > m) m = key[3];
        #pragma unroll
        for (int off = 32; off > 0; off >>= 1){
            unsigned long long o = __shfl_xor(m, off);
            if (o > m) m = o;
        }
        if      (key[0] == m) key[0] = 0ull;   // unique keys: exactly one owner
        else if (key[1] == m) key[1] = 0ull;
        else if (key[2] == m) key[2] = 0ull;
        else if (key[3] == m) key[3] = 0ull;
        unsigned int um = (unsigned int)(m >> 32);
        unsigned int ou = (um & 0x80000000u) ? (um & 0x7FFFFFFFu) : ~um;
        wv[sel]  = __uint_as_float(ou);
        widx[sel] = (int)~((unsigned int)m);
        k16 = m;
    }

    // certificate: does any chunk's stored 8th outrank the 16th selected?
    bool fl = false;
    #pragma unroll
    for (int s = 0; s < 4; ++s){
        int slot = lane + 64*s;
        if ((slot % TCH) == TCH-1 && okey[s] > k16) fl = true;
    }
    if (__ballot(fl) == 0ull){
        if (lane == 0){
            #pragma unroll
            for (int sel = 0; sel < KNB; ++sel){
                topIdx[q*KNB + sel] = widx[sel];
                ewArr [q*KNB + sel] = (wv[sel] > 0.5f) ? wv[sel] : 0.0f;
            }
        }
        return;
    }
    if (lane != 0) return;

    // ---- serial exact fallback (round-11 code; P(reach) ~ 3e-7/query) ----
    float lv[16]; int li[16];
    #pragma unroll
    for (int r = 0; r < 16; ++r){ lv[r] = -3.0e38f; li[r] = INT_MAX; }
    unsigned int flags = 0;
    for (int c = 0; c < NSPL; ++c){
        float v8 = chV[(size_t)(c*TCH + TCH-1)*N + q];
        int  i8 = chI[(size_t)(c*TCH + TCH-1)*N + q];
        if (v8 > wv[15] || (v8 == wv[15] && i8 < widx[15])) flags |= (1u << c);
    }
    const float4* xq4 = (const float4*)(xf + (size_t)q*D);
    float4 xq[16];
    #pragma unroll
    for (int c = 0; c < 16; ++c) xq[c] = xq4[c];
    float ni = nrmf[q];
    for (int c = 0; c < NSPL; ++c){
        if ((flags >> c) & 1u){
            for (int j = c*JSPAN; j < c*JSPAN + JSPAN; ++j){
                if (j == q) continue;
                const float4* b4 = (const float4*)(xf + (size_t)j*D);
                float a = 0.0f;
                #pragma unroll
                for (int k = 0; k < 16; ++k){
                    float4 b = b4[k]; float4 xa = xq[k];
                    a = __fmaf_rn(b.x, xa.x, a);
                    a = __fmaf_rn(b.y, xa.y, a);
                    a = __fmaf_rn(b.z, xa.z, a);
                    a = __fmaf_rn(b.w, xa.w, a);
                }
                float den = __fadd_rn(__fmul_rn(ni, nrmf[j]), 1e-8f);
                float s0 = __fdiv_rn(a, den);
                if (s0 > lv[15] || (s0 == lv[15] && j < li[15])){
                    lv[15] = s0; li[15] = j;
                    #pragma unroll
                    for (int k = 15; k > 0; --k){
                        if (lv[k] > lv[k-1] || (lv[k] == lv[k-1] && li[k] < li[k-1])){
                            float tv = lv[k]; lv[k] = lv[k-1]; lv[k-1] = tv;
                            int ti = li[k]; li[k] = li[k-1]; li[k-1] = ti;
                        }
                    }
                }
            }
        } else {
            #pragma unroll
            for (int r = 0; r < TCH; ++r){
                float v = chV[(size_t)(c*TCH + r)*N + q];
                int  id = chI[(size_t)(c*TCH + r)*N + q];
                if (v > lv[15] || (v == lv[15] && id < li[15])){
                    lv[15] = v; li[15] = id;
                    #pragma unroll
                    for (int k = 15; k > 0; --k){
                        if (lv[k] > lv[k-1] || (lv[k] == lv[k-1] && li[k] < li[k-1])){
                            float tv = lv[k]; lv[k] = lv[k-1]; lv[k-1] = tv;
                            int ti = li[k]; li[k] = li[k-1]; li[k-1] = ti;
                        }
                    }
                }
            }
        }
    }
    #pragma unroll
    for (int sel = 0; sel < KNB; ++sel){
        topIdx[q*KNB + sel] = li[sel];
        ewArr [q*KNB + sel] = (lv[sel] > 0.5f) ? lv[sel] : 0.0f;
    }
}

// ---------------- degree / dinv ----------------
__global__ void k_deg_init(double* __restrict__ degD){
    int j = blockIdx.x*blockDim.x + threadIdx.x;
    if (j < N) degD[j] = 2.0;
}
__global__ void k_deg_scatter(const int* __restrict__ topIdx, const float* __restrict__ ewArr,
                              double* __restrict__ degD){
    int e = blockIdx.x*blockDim.x + threadIdx.x;
    if (e < NE){
        float w = ewArr[e];
        if (w > 0.0f) atomicAdd(&degD[topIdx[e]], (double)w);
    }
}
__global__ void k_dinv(const double* __restrict__ degD, float* __restrict__ dinv){
    int j = blockIdx.x*blockDim.x + threadIdx.x;
    if (j < N) dinv[j] = (float)(1.0 / sqrt(degD[j]));
}

// ---------------- dense matmuls ----------------
__global__ void k_gemm1(const float* __restrict__ xf, const float* __restrict__ W1,
                        float* __restrict__ h1){
    int id = blockIdx.x*256 + threadIdx.x;
    int i = id >> 7; int f = id & (H-1);
    const float* xr = xf + i*D;
    float acc = 0.f;
    #pragma unroll
    for (int k = 0; k < D; ++k) acc += xr[k] * W1[k*H + f];
    h1[id] = acc;
}
__global__ void k_gemm2(const float* __restrict__ z1, const float* __restrict__ W2,
                        float* __restrict__ h2){
    int id = blockIdx.x*256 + threadIdx.x;
    int i = id >> 6; int f = id & (O-1);
    const float* zr = z1 + i*H;
    float acc = 0.f;
    #pragma unroll
    for (int k = 0; k < H; ++k) acc += zr[k] * W2[k*O + f];
    h2[id] = acc;
}
__global__ void k_proj(const float* __restrict__ z2, const float* __restrict__ Wp,
                       const float* __restrict__ bp, float* __restrict__ z3){
    int id = blockIdx.x*256 + threadIdx.x;
    int i = id >> 6; int f = id & (D-1);
    const float* zr = z2 + i*O;
    float acc = bp[f];
    #pragma unroll
    for (int k = 0; k < O; ++k) acc += zr[k] * Wp[k*D + f];
    z3[id] = acc;
}

// ---------------- GCN aggregation ----------------
template<int F>
__global__ void k_agg_init(const float* __restrict__ h, const float* __restrict__ dinv,
                           float* __restrict__ agg){
    int id = blockIdx.x*256 + threadIdx.x;
    int j = id / F;
    float dj = dinv[j];
    agg[id] = 2.f * dj * dj * h[id];
}
template<int F>
__global__ void k_agg_scat(const int* __restrict__ topIdx, const float* __restrict__ ewArr,
                           const float* __restrict__ dinv, const float* __restrict__ h,
                           float* __restrict__ agg){
    int e = blockIdx.x; int f = threadIdx.x;
    float w = ewArr[e];
    if (w == 0.f) return;
    int s = e >> 4;
    int dn = topIdx[e];
    float c = dinv[s] * w * dinv[dn];
    atomicAdd(&agg[dn*F + f], c * h[s*F + f]);
}

// ---------------- bias + relu + layernorm ----------------
__global__ void k_post128(const float* __restrict__ agg, const float* __restrict__ b,
                          const float* __restrict__ g, const float* __restrict__ be,
                          float* __restrict__ z){
    __shared__ double s2[2];
    __shared__ double s3[2];
    int i = blockIdx.x; int f = threadIdx.x;
    float v = agg[i*H + f] + b[f];
    v = v > 0.f ? v : 0.f;
    int wid = f >> 6;
    double d = (double)v;
    for (int off = 32; off > 0; off >>= 1) d += __shfl_xor(d, off);
    if ((f & 63) == 0) s2[wid] = d;
    __syncthreads();
    double mu = (s2[0] + s2[1]) * (1.0/128.0);
    double dv = (double)v - mu;
    double qq = dv * dv;
    for (int off = 32; off > 0; off >>= 1) qq += __shfl_xor(qq, off);
    if ((f & 63) == 0) s3[wid] = qq;
    __syncthreads();
    double var = (s3[0] + s3[1]) * (1.0/128.0);
    double rs = 1.0 / sqrt(var + 1e-5);
    z[i*H + f] = (float)(dv * rs * (double)g[f] + (double)be[f]);
}
__global__ void k_post64(const float* __restrict__ agg, const float* __restrict__ b,
                         const float* __restrict__ g, const float* __restrict__ be,
                         float* __restrict__ z){
    int i = blockIdx.x; int f = threadIdx.x;
    float v = agg[i*O + f] + b[f];
    v = v > 0.f ? v : 0.f;
    double d = (double)v;
    for (int off = 32; off > 0; off >>= 1) d += __shfl_xor(d, off);
    double mu = d * (1.0/64.0);
    double dv = (double)v - mu;
    double qq = dv * dv;
    for (int off = 32; off > 0; off >>= 1) qq += __shfl_xor(qq, off);
    double var = qq * (1.0/64.0);
    double rs = 1.0 / sqrt(var + 1e-5);
    z[i*O + f] = (float)(dv * rs * (double)g[f] + (double)be[f]);
}

// ---------------- fused output store + edges (flag-branched dtype) ----------------
__global__ void k_out(const float* __restrict__ z3, const int* __restrict__ topIdx,
                      const float* __restrict__ ewArr, void* __restrict__ outp,
                      const int* __restrict__ flag){
    int id = blockIdx.x*256 + threadIdx.x;
    if (id < OUT0){
        float v = z3[id];
        if (*flag) ((unsigned short*)outp)[id] = f2bf(v);
        else       ((float*)outp)[id] = v;
        return;
    }
    int e = id - OUT0;
    if (e >= ETOT) return;
    int s, dn; float w;
    if (e < NE){ s = e >> 4; dn = topIdx[e]; w = ewArr[e]; }
    else       { s = e - NE; dn = s;        w = 1.0f; }
    if (*flag){
        unsigned short* o = (unsigned short*)outp;
        o[OUT0 + e]          = f2bf((float)s);
        o[OUT0 + ETOT + e]   = f2bf((float)dn);
        o[OUT0 + 2*ETOT + e] = f2bf(w);
    } else {
        float* o = (float*)outp;
        o[OUT0 + e]          = (float)s;
        o[OUT0 + ETOT + e]   = (float)dn;
        o[OUT0 + 2*ETOT + e] = w;
    }
}

extern "C" void kernel_launch(void* const* d_in, const int* in_sizes, int n_in,
                              void* d_out, int out_size, void* d_ws, size_t ws_size,
                              hipStream_t stream){
    char* ws = (char*)d_ws;
    int*    flag   = (int*)   (ws + 0);
    float*  w1f    = (float*) (ws + 4096);
    float*  b1f    = (float*) (ws + 36864);
    float*  g1f    = (float*) (ws + 37376);
    float*  be1f   = (float*) (ws + 37888);
    float*  w2f    = (float*) (ws + 38400);
    float*  b2f    = (float*) (ws + 71168);
    float*  g2f    = (float*) (ws + 71424);
    float*  be2f   = (float*) (ws + 71680);
    float*  wpf    = (float*) (ws + 71936);
    float*  bpf    = (float*) (ws + 88320);
    float*  xf     = (float*) (ws + 98304);      // 2 MB          -> 2195456
    float*  nrmf   = (float*) (ws + 2195456);    // 32 KB         -> 2228224
    int*    topIdx = (int*)   (ws + 2260992);    // 512 KB        -> 2785280
    float*  ewArr  = (float*) (ws + 2785280);    // 512 KB        -> 3309568
    double* degD   = (double*)(ws + 3309568);    // 64 KB         -> 3375104
    float*  dinv   = (float*) (ws + 3375104);    // 32 KB         -> 3407872
    float*  h1     = (float*) (ws + 3407872);    // 4 MB          -> 7602176
    float*  agg1   = (float*) (ws + 7602176);    // 4 MB          -> 11796480
    float*  z1     = (float*) (ws + 11796480);   // 4 MB          -> 15990784
    float*  h2     = h1;
    float*  agg2   = agg1;
    float*  z2     = z1;
    float*  z3     = h1;

    // topk scratch overlaps h1/agg1/z1 (all dead until k_gemm1, which
    // launches after k_sel16): chV 8.39 MB @3407872, chI 8.39 MB
    // @11796480, end 20185088 — within ws (round 3 used ~37 MB here).
    float* chV = (float*)(ws + 3407872);
    int*   chI = (int*)  (ws + 11796480);

    k_probe<<<1, 256, 0, stream>>>((const unsigned short*)d_in[0], flag);
    k_cvt<<<(N*D+255)/256, 256, 0, stream>>>(d_in[0], xf,  N*D, flag);
    k_cvtp<<<(21120+255)/256, 256, 0, stream>>>(
        d_in[1], d_in[2], d_in[3], d_in[4], d_in[5],
        d_in[6], d_in[7], d_in[8], d_in[9], d_in[10],
        w1f, b1f, g1f, be1f, w2f, b2f, g2f, be2f, wpf, bpf, flag);

    k_prep<<<N/64, 64, 0, stream>>>(xf, nrmf);
    k_scan8<<<32*NSPL, 256, 0, stream>>>(xf, nrmf, chV, chI);
    k_sel16<<<(N*64)/256, 256, 0, stream>>>(xf, nrmf, chV, chI, topIdx, ewArr);

    k_deg_init<<<N/256, 256, 0, stream>>>(degD);
    k_deg_scatter<<<NE/256, 256, 0, stream>>>(topIdx, ewArr, degD);
    k_dinv<<<N/256, 256, 0, stream>>>(degD, dinv);

    k_gemm1<<<(N*H)/256, 256, 0, stream>>>(xf, w1f, h1);
    k_agg_init<H><<<(N*H)/256, 256, 0, stream>>>(h1, dinv, agg1);
    k_agg_scat<H><<<NE, H, 0, stream>>>(topIdx, ewArr, dinv, h1, agg1);
    k_post128<<<N, H, 0, stream>>>(agg1, b1f, g1f, be1f, z1);

    k_gemm2<<<(N*O)/256, 256, 0, stream>>>(z1, w2f, h2);
    k_agg_init<O><<<(N*O)/256, 256, 0, stream>>>(h2, dinv, agg2);
    k_agg_scat<O><<<NE, O, 0, stream>>>(topIdx, ewArr, dinv, h2, agg2);
    k_post64<<<N, O, 0, stream>>>(agg2, b2f, g2f, be2f, z2);

    k_proj<<<(N*D)/256, 256, 0, stream>>>(z2, wpf, bpf, z3);
    k_out<<<(OUT0+ETOT+255)/256, 256, 0, stream>>>(z3, topIdx, ewArr, d_out, flag);
}

// Round 16
// 439.586 us; speedup vs baseline: 5.0063x; 1.0357x over previous
//
#include <hip/hip_runtime.h>
#include <cstdint>
#include <climits>

#define N 8192
#define D 64
#define H 128
#define O 64
#define KNB 16
#define NE (N*KNB)        // 131072
#define ETOT (NE + N)     // 139264
#define OUT0 (N*D)        // 524288
#define NSPL 32           // j-splits (chunks)
#define JSPAN 256         // j's per chunk (N/NSPL)
#define TCH 8             // stored top-T per chunk (certificate depth)

__device__ __forceinline__ float bf2f(unsigned short u){
    union { unsigned int u; float f; } v; v.u = ((unsigned int)u) << 16; return v.f;
}
__device__ __forceinline__ unsigned short f2bf(float f){
    union { float f; unsigned int u; } v; v.f = f;
    unsigned int r = v.u + 0x7FFFu + ((v.u >> 16) & 1u);   // RNE
    return (unsigned short)(r >> 16);
}

#define PIN4(v) asm volatile("" : "+v"((v).x), "+v"((v).y), "+v"((v).z), "+v"((v).w))

// ---------------- dtype probe: 1=bf16 inputs, 0=fp32 inputs ----------------
__global__ void k_probe(const unsigned short* __restrict__ x, int* __restrict__ flag){
    __shared__ int cnt;
    if (threadIdx.x == 0) cnt = 0;
    __syncthreads();
    unsigned short u = x[2*threadIdx.x];
    int e = (u >> 7) & 0xFF;
    int ok = (u == 0) || (e >= 0x60 && e <= 0x85);
    unsigned long long m = __ballot(ok);
    if ((threadIdx.x & 63) == 0) atomicAdd(&cnt, __popcll(m));
    __syncthreads();
    if (threadIdx.x == 0) *flag = (cnt >= 128) ? 1 : 0;
}

// ---------------- x convert -> fp32 ----------------
__global__ void k_cvt(const void* __restrict__ src, float* __restrict__ dst,
                      int n, const int* __restrict__ flag){
    int i = blockIdx.x*256 + threadIdx.x;
    if (i >= n) return;
    if (*flag) dst[i] = bf2f(((const unsigned short*)src)[i]);
    else       dst[i] = ((const float*)src)[i];
}

// ---------------- fused param convert (10 tensors, one launch) ----------------
__global__ void k_cvtp(const void* s1, const void* s2, const void* s3, const void* s4,
                       const void* s5, const void* s6, const void* s7, const void* s8,
                       const void* s9, const void* s10,
                       float* d1, float* d2, float* d3, float* d4, float* d5,
                       float* d6, float* d7, float* d8, float* d9, float* d10,
                       const int* __restrict__ flag){
    int id = blockIdx.x*256 + threadIdx.x;
    const void* s; float* d; int off;
    if      (id <  8192){ s = s1;  d = d1;  off = id; }
    else if (id <  8320){ s = s2;  d = d2;  off = id - 8192; }
    else if (id <  8448){ s = s3;  d = d3;  off = id - 8320; }
    else if (id <  8576){ s = s4;  d = d4;  off = id - 8448; }
    else if (id < 16768){ s = s5;  d = d5;  off = id - 8576; }
    else if (id < 16832){ s = s6;  d = d6;  off = id - 16768; }
    else if (id < 16896){ s = s7;  d = d7;  off = id - 16832; }
    else if (id < 16960){ s = s8;  d = d8;  off = id - 16896; }
    else if (id < 21056){ s = s9;  d = d9;  off = id - 16960; }
    else if (id < 21120){ s = s10; d = d10; off = id - 21056; }
    else return;
    if (*flag) d[off] = bf2f(((const unsigned short*)s)[off]);
    else       d[off] = ((const float*)s)[off];
}

// ---------------- row norms: EXACT numpy fp32 pairwise semantics ----------------
__global__ void k_prep(const float* __restrict__ xf, float* __restrict__ nrmf){
    int i = blockIdx.x*64 + threadIdx.x;
    const float* xr = xf + i*D;
    float r[8];
    #pragma unroll
    for (int q = 0; q < 8; ++q) r[q] = __fmul_rn(xr[q], xr[q]);
    #pragma unroll
    for (int b = 8; b < 64; b += 8)
        #pragma unroll
        for (int q = 0; q < 8; ++q)
            r[q] = __fadd_rn(r[q], __fmul_rn(xr[b+q], xr[b+q]));
    float s = __fadd_rn(__fadd_rn(__fadd_rn(r[0],r[1]), __fadd_rn(r[2],r[3])),
                        __fadd_rn(__fadd_rn(r[4],r[5]), __fadd_rn(r[6],r[7])));
    nrmf[i] = __fsqrt_rn(s);
}

// =====================================================================
// Single-scan exact top-k with per-chunk top-8 certificate.
// ROUND-15 POST-MORTEM: LDS-broadcast j-rows cost full per-lane
// replication BW on the DS pipe (16 b128/j/wave, ~1KB replicated each,
// ~8cyc) -> 16 waves/CU x 256j x 16 x 8 = 218us ~= the measured 225us.
// Fix: wave-uniform GLOBAL j-row -> compiler scalarizes it to s_load
// chains (round-5 measured SGPR=96) and FMAs become v_fmac v,s,v with
// ZERO in-loop DS/VMEM. Round-5/6's failure mode (xi4 demoted to 40
// VGPRs, reloaded per-j) is countered with amdgpu_waves_per_eu(4,4):
// occupancy target pinned at 4 waves/EU (= all our 1024-block grid can
// use), 128-VGPR budget, removing the remat-for-occupancy incentive.
// FALSIFIABLE: if VGPR_Count stays <=64, the fix failed -> revert to
// the LDS scan next round.
// CERTIFICATE (proven r15): elements not stored for chunk c rank below
// c's stored 8th; if no chunk's 8th outranks the provisional 16th, the
// 256-candidate union top-16 is exact. P(fire) ~ 3.7e-7/query.
// Sim chain (bitwise-stable, operand-source independent):
//   a = fma-chain k=0..63; den = fadd(fmul(ni,nj),1e-8); s = fdiv(a,den).
// =====================================================================

__global__ __launch_bounds__(256)
__attribute__((amdgpu_waves_per_eu(4,4)))
void k_scan8(const float* __restrict__ xf,
             const float* __restrict__ nrmf,
             float* __restrict__ chV,
             int* __restrict__ chI){
    int tid = threadIdx.x;
    int grp = blockIdx.x & 31;        // 32 query groups of 256
    int split = blockIdx.x >> 5;      // 32 chunks
    int i = grp*256 + tid;
    int jbase = split*JSPAN;

    const float4* xip = (const float4*)(xf + (size_t)i*D);
    float4 xi4[16];
    #pragma unroll
    for (int c = 0; c < 16; ++c) xi4[c] = xip[c];
    #pragma unroll
    for (int c = 0; c < 16; ++c) PIN4(xi4[c]);
    float ni = nrmf[i];

    float lv[TCH]; int li[TCH];
    #pragma unroll
    for (int r = 0; r < TCH; ++r){ lv[r] = -3.0e38f; li[r] = INT_MAX; }

    for (int jj = 0; jj < JSPAN; ++jj){
        int j = jbase + jj;                         // wave-uniform
        const float4* A = (const float4*)(xf + (size_t)j*D);
        float nj = nrmf[j];
        float a = 0.0f;
        #pragma unroll
        for (int c = 0; c < 16; ++c){
            float4 b = A[c]; float4 xa = xi4[c];    // b uniform -> s_load
            a = __fmaf_rn(b.x, xa.x, a);
            a = __fmaf_rn(b.y, xa.y, a);
            a = __fmaf_rn(b.z, xa.z, a);
            a = __fmaf_rn(b.w, xa.w, a);
        }
        float den = __fadd_rn(__fmul_rn(ni, nj), 1e-8f);
        float thr = lv[TCH-1]*den;
        // conservative prefilter (margin >> fdiv rounding), exact recheck
        if (j != i && a > __fmaf_rn(fabsf(thr), -1e-6f, thr)){
            float s0 = __fdiv_rn(a, den);
            if (s0 > lv[TCH-1]){   // strict >: ties keep earlier idx (idx-asc rank)
                lv[TCH-1] = s0; li[TCH-1] = j;
                #pragma unroll
                for (int r = TCH-1; r > 0; --r){
                    if (lv[r] > lv[r-1]){
                        float tv = lv[r]; lv[r] = lv[r-1]; lv[r-1] = tv;
                        int ti = li[r]; li[r] = li[r-1]; li[r-1] = ti;
                    }
                }
            }
        }
    }
    // transposed layout: [(split*TCH+r)*N + i] — coalesced store
    #pragma unroll
    for (int r = 0; r < TCH; ++r){
        chV[(size_t)(split*TCH + r)*N + i] = lv[r];
        chI[(size_t)(split*TCH + r)*N + i] = li[r];
    }
}

// ---- wave-per-query exact top-16 of the 256-candidate union ----
__global__ __launch_bounds__(256, 2) void k_sel16(const float* __restrict__ xf,
                                                  const float* __restrict__ nrmf,
                                                  const float* __restrict__ chV,
                                                  const int* __restrict__ chI,
                                                  int* __restrict__ topIdx,
                                                  float* __restrict__ ewArr){
    int q = (blockIdx.x*256 + threadIdx.x) >> 6;   // one wave per query
    int lane = threadIdx.x & 63;

    // load 4 slots per lane as order-preserving 64-bit keys
    unsigned long long okey[4], key[4];
    #pragma unroll
    for (int s = 0; s < 4; ++s){
        int slot = lane + 64*s;
        float v = chV[(size_t)slot*N + q];
        int  id = chI[(size_t)slot*N + q];
        unsigned int u = __float_as_uint(v);
        if ((u & 0x7FFFFFFFu) == 0u) u = 0u;              // -0 -> +0
        u = (u & 0x80000000u) ? ~u : (u | 0x80000000u);   // monotone float map
        unsigned long long kk = ((unsigned long long)u << 32)
                              | (unsigned long long)(unsigned int)(~(unsigned int)id);
        okey[s] = kk; key[s] = kk;
    }

    float wv[16]; int widx[16];
    unsigned long long k16 = 0ull;
    #pragma unroll
    for (int sel = 0; sel < KNB; ++sel){
        unsigned long long m = key[0] > key[1] ? key[0] : key[1];
        if (key[2] > m) m = key[2];
        if (key[3] > m) m = key[3];
        #pragma unroll
        for (int off = 32; off > 0; off >>= 1){
            unsigned long long o = __shfl_xor(m, off);
            if (o > m) m = o;
        }
        if      (key[0] == m) key[0] = 0ull;   // unique keys: exactly one owner
        else if (key[1] == m) key[1] = 0ull;
        else if (key[2] == m) key[2] = 0ull;
        else if (key[3] == m) key[3] = 0ull;
        unsigned int um = (unsigned int)(m >> 32);
        unsigned int ou = (um & 0x80000000u) ? (um & 0x7FFFFFFFu) : ~um;
        wv[sel]  = __uint_as_float(ou);
        widx[sel] = (int)~((unsigned int)m);
        k16 = m;
    }

    // certificate: does any chunk's stored 8th outrank the 16th selected?
    bool fl = false;
    #pragma unroll
    for (int s = 0; s < 4; ++s){
        int slot = lane + 64*s;
        if ((slot % TCH) == TCH-1 && okey[s] > k16) fl = true;
    }
    if (__ballot(fl) == 0ull){
        if (lane == 0){
            #pragma unroll
            for (int sel = 0; sel < KNB; ++sel){
                topIdx[q*KNB + sel] = widx[sel];
                ewArr [q*KNB + sel] = (wv[sel] > 0.5f) ? wv[sel] : 0.0f;
            }
        }
        return;
    }
    if (lane != 0) return;

    // ---- serial exact fallback (round-11 code; P(reach) ~ 3e-7/query) ----
    float lv[16]; int li[16];
    #pragma unroll
    for (int r = 0; r < 16; ++r){ lv[r] = -3.0e38f; li[r] = INT_MAX; }
    unsigned int flags = 0;
    for (int c = 0; c < NSPL; ++c){
        float v8 = chV[(size_t)(c*TCH + TCH-1)*N + q];
        int  i8 = chI[(size_t)(c*TCH + TCH-1)*N + q];
        if (v8 > wv[15] || (v8 == wv[15] && i8 < widx[15])) flags |= (1u << c);
    }
    const float4* xq4 = (const float4*)(xf + (size_t)q*D);
    float4 xq[16];
    #pragma unroll
    for (int c = 0; c < 16; ++c) xq[c] = xq4[c];
    float ni = nrmf[q];
    for (int c = 0; c < NSPL; ++c){
        if ((flags >> c) & 1u){
            for (int j = c*JSPAN; j < c*JSPAN + JSPAN; ++j){
                if (j == q) continue;
                const float4* b4 = (const float4*)(xf + (size_t)j*D);
                float a = 0.0f;
                #pragma unroll
                for (int k = 0; k < 16; ++k){
                    float4 b = b4[k]; float4 xa = xq[k];
                    a = __fmaf_rn(b.x, xa.x, a);
                    a = __fmaf_rn(b.y, xa.y, a);
                    a = __fmaf_rn(b.z, xa.z, a);
                    a = __fmaf_rn(b.w, xa.w, a);
                }
                float den = __fadd_rn(__fmul_rn(ni, nrmf[j]), 1e-8f);
                float s0 = __fdiv_rn(a, den);
                if (s0 > lv[15] || (s0 == lv[15] && j < li[15])){
                    lv[15] = s0; li[15] = j;
                    #pragma unroll
                    for (int k = 15; k > 0; --k){
                        if (lv[k] > lv[k-1] || (lv[k] == lv[k-1] && li[k] < li[k-1])){
                            float tv = lv[k]; lv[k] = lv[k-1]; lv[k-1] = tv;
                            int ti = li[k]; li[k] = li[k-1]; li[k-1] = ti;
                        }
                    }
                }
            }
        } else {
            #pragma unroll
            for (int r = 0; r < TCH; ++r){
                float v = chV[(size_t)(c*TCH + r)*N + q];
                int  id = chI[(size_t)(c*TCH + r)*N + q];
                if (v > lv[15] || (v == lv[15] && id < li[15])){
                    lv[15] = v; li[15] = id;
                    #pragma unroll
                    for (int k = 15; k > 0; --k){
                        if (lv[k] > lv[k-1] || (lv[k] == lv[k-1] && li[k] < li[k-1])){
                            float tv = lv[k]; lv[k] = lv[k-1]; lv[k-1] = tv;
                            int ti = li[k]; li[k] = li[k-1]; li[k-1] = ti;
                        }
                    }
                }
            }
        }
    }
    #pragma unroll
    for (int sel = 0; sel < KNB; ++sel){
        topIdx[q*KNB + sel] = li[sel];
        ewArr [q*KNB + sel] = (lv[sel] > 0.5f) ? lv[sel] : 0.0f;
    }
}

// ---------------- degree / dinv ----------------
__global__ void k_deg_init(double* __restrict__ degD){
    int j = blockIdx.x*blockDim.x + threadIdx.x;
    if (j < N) degD[j] = 2.0;
}
__global__ void k_deg_scatter(const int* __restrict__ topIdx, const float* __restrict__ ewArr,
                              double* __restrict__ degD){
    int e = blockIdx.x*blockDim.x + threadIdx.x;
    if (e < NE){
        float w = ewArr[e];
        if (w > 0.0f) atomicAdd(&degD[topIdx[e]], (double)w);
    }
}
__global__ void k_dinv(const double* __restrict__ degD, float* __restrict__ dinv){
    int j = blockIdx.x*blockDim.x + threadIdx.x;
    if (j < N) dinv[j] = (float)(1.0 / sqrt(degD[j]));
}

// ---------------- dense matmuls ----------------
__global__ void k_gemm1(const float* __restrict__ xf, const float* __restrict__ W1,
                        float* __restrict__ h1){
    int id = blockIdx.x*256 + threadIdx.x;
    int i = id >> 7; int f = id & (H-1);
    const float* xr = xf + i*D;
    float acc = 0.f;
    #pragma unroll
    for (int k = 0; k < D; ++k) acc += xr[k] * W1[k*H + f];
    h1[id] = acc;
}
__global__ void k_gemm2(const float* __restrict__ z1, const float* __restrict__ W2,
                        float* __restrict__ h2){
    int id = blockIdx.x*256 + threadIdx.x;
    int i = id >> 6; int f = id & (O-1);
    const float* zr = z1 + i*H;
    float acc = 0.f;
    #pragma unroll
    for (int k = 0; k < H; ++k) acc += zr[k] * W2[k*O + f];
    h2[id] = acc;
}
__global__ void k_proj(const float* __restrict__ z2, const float* __restrict__ Wp,
                       const float* __restrict__ bp, float* __restrict__ z3){
    int id = blockIdx.x*256 + threadIdx.x;
    int i = id >> 6; int f = id & (D-1);
    const float* zr = z2 + i*O;
    float acc = bp[f];
    #pragma unroll
    for (int k = 0; k < O; ++k) acc += zr[k] * Wp[k*D + f];
    z3[id] = acc;
}

// ---------------- GCN aggregation ----------------
template<int F>
__global__ void k_agg_init(const float* __restrict__ h, const float* __restrict__ dinv,
                           float* __restrict__ agg){
    int id = blockIdx.x*256 + threadIdx.x;
    int j = id / F;
    float dj = dinv[j];
    agg[id] = 2.f * dj * dj * h[id];
}
// Grid-stride, WAVE-per-edge (round-15 tail fix: the old layout dispatched
// 131072 one-edge workgroups; this uses 4096 blocks x 4 waves). w==0 exit
// is wave-uniform (one edge per wave). h reads/atomics coalesced per wave.
template<int F>
__global__ __launch_bounds__(256) void k_agg_scat(const int* __restrict__ topIdx,
                                                  const float* __restrict__ ewArr,
                                                  const float* __restrict__ dinv,
                                                  const float* __restrict__ h,
                                                  float* __restrict__ agg){
    int wid = threadIdx.x >> 6;
    int lane = threadIdx.x & 63;
    for (int e = blockIdx.x*4 + wid; e < NE; e += gridDim.x*4){
        float w = ewArr[e];
        if (w == 0.f) continue;
        int s = e >> 4;
        int dn = topIdx[e];
        float c = dinv[s] * w * dinv[dn];
        #pragma unroll
        for (int p = 0; p < F/64; ++p){
            int f = lane + 64*p;
            atomicAdd(&agg[dn*F + f], c * h[s*F + f]);
        }
    }
}

// ---------------- bias + relu + layernorm ----------------
__global__ void k_post128(const float* __restrict__ agg, const float* __restrict__ b,
                          const float* __restrict__ g, const float* __restrict__ be,
                          float* __restrict__ z){
    __shared__ double s2[2];
    __shared__ double s3[2];
    int i = blockIdx.x; int f = threadIdx.x;
    float v = agg[i*H + f] + b[f];
    v = v > 0.f ? v : 0.f;
    int wid = f >> 6;
    double d = (double)v;
    for (int off = 32; off > 0; off >>= 1) d += __shfl_xor(d, off);
    if ((f & 63) == 0) s2[wid] = d;
    __syncthreads();
    double mu = (s2[0] + s2[1]) * (1.0/128.0);
    double dv = (double)v - mu;
    double qq = dv * dv;
    for (int off = 32; off > 0; off >>= 1) qq += __shfl_xor(qq, off);
    if ((f & 63) == 0) s3[wid] = qq;
    __syncthreads();
    double var = (s3[0] + s3[1]) * (1.0/128.0);
    double rs = 1.0 / sqrt(var + 1e-5);
    z[i*H + f] = (float)(dv * rs * (double)g[f] + (double)be[f]);
}
__global__ void k_post64(const float* __restrict__ agg, const float* __restrict__ b,
                         const float* __restrict__ g, const float* __restrict__ be,
                         float* __restrict__ z){
    int i = blockIdx.x; int f = threadIdx.x;
    float v = agg[i*O + f] + b[f];
    v = v > 0.f ? v : 0.f;
    double d = (double)v;
    for (int off = 32; off > 0; off >>= 1) d += __shfl_xor(d, off);
    double mu = d * (1.0/64.0);
    double dv = (double)v - mu;
    double qq = dv * dv;
    for (int off = 32; off > 0; off >>= 1) qq += __shfl_xor(qq, off);
    double var = qq * (1.0/64.0);
    double rs = 1.0 / sqrt(var + 1e-5);
    z[i*O + f] = (float)(dv * rs * (double)g[f] + (double)be[f]);
}

// ---------------- fused output store + edges (flag-branched dtype) ----------------
__global__ void k_out(const float* __restrict__ z3, const int* __restrict__ topIdx,
                      const float* __restrict__ ewArr, void* __restrict__ outp,
                      const int* __restrict__ flag){
    int id = blockIdx.x*256 + threadIdx.x;
    if (id < OUT0){
        float v = z3[id];
        if (*flag) ((unsigned short*)outp)[id] = f2bf(v);
        else       ((float*)outp)[id] = v;
        return;
    }
    int e = id - OUT0;
    if (e >= ETOT) return;
    int s, dn; float w;
    if (e < NE){ s = e >> 4; dn = topIdx[e]; w = ewArr[e]; }
    else       { s = e - NE; dn = s;        w = 1.0f; }
    if (*flag){
        unsigned short* o = (unsigned short*)outp;
        o[OUT0 + e]          = f2bf((float)s);
        o[OUT0 + ETOT + e]   = f2bf((float)dn);
        o[OUT0 + 2*ETOT + e] = f2bf(w);
    } else {
        float* o = (float*)outp;
        o[OUT0 + e]          = (float)s;
        o[OUT0 + ETOT + e]   = (float)dn;
        o[OUT0 + 2*ETOT + e] = w;
    }
}

extern "C" void kernel_launch(void* const* d_in, const int* in_sizes, int n_in,
                              void* d_out, int out_size, void* d_ws, size_t ws_size,
                              hipStream_t stream){
    char* ws = (char*)d_ws;
    int*    flag   = (int*)   (ws + 0);
    float*  w1f    = (float*) (ws + 4096);
    float*  b1f    = (float*) (ws + 36864);
    float*  g1f    = (float*) (ws + 37376);
    float*  be1f   = (float*) (ws + 37888);
    float*  w2f    = (float*) (ws + 38400);
    float*  b2f    = (float*) (ws + 71168);
    float*  g2f    = (float*) (ws + 71424);
    float*  be2f   = (float*) (ws + 71680);
    float*  wpf    = (float*) (ws + 71936);
    float*  bpf    = (float*) (ws + 88320);
    float*  xf     = (float*) (ws + 98304);      // 2 MB          -> 2195456
    float*  nrmf   = (float*) (ws + 2195456);    // 32 KB         -> 2228224
    int*    topIdx = (int*)   (ws + 2260992);    // 512 KB        -> 2785280
    float*  ewArr  = (float*) (ws + 2785280);    // 512 KB        -> 3309568
    double* degD   = (double*)(ws + 3309568);    // 64 KB         -> 3375104
    float*  dinv   = (float*) (ws + 3375104);    // 32 KB         -> 3407872
    float*  h1     = (float*) (ws + 3407872);    // 4 MB          -> 7602176
    float*  agg1   = (float*) (ws + 7602176);    // 4 MB          -> 11796480
    float*  z1     = (float*) (ws + 11796480);   // 4 MB          -> 15990784
    float*  h2     = h1;
    float*  agg2   = agg1;
    float*  z2     = z1;
    float*  z3     = h1;

    // topk scratch overlaps h1/agg1/z1 (all dead until k_gemm1, which
    // launches after k_sel16): chV 8.39 MB @3407872, chI 8.39 MB
    // @11796480, end 20185088 — within ws (round 3 used ~37 MB here).
    float* chV = (float*)(ws + 3407872);
    int*   chI = (int*)  (ws + 11796480);

    k_probe<<<1, 256, 0, stream>>>((const unsigned short*)d_in[0], flag);
    k_cvt<<<(N*D+255)/256, 256, 0, stream>>>(d_in[0], xf,  N*D, flag);
    k_cvtp<<<(21120+255)/256, 256, 0, stream>>>(
        d_in[1], d_in[2], d_in[3], d_in[4], d_in[5],
        d_in[6], d_in[7], d_in[8], d_in[9], d_in[10],
        w1f, b1f, g1f, be1f, w2f, b2f, g2f, be2f, wpf, bpf, flag);

    k_prep<<<N/64, 64, 0, stream>>>(xf, nrmf);
    k_scan8<<<32*NSPL, 256, 0, stream>>>(xf, nrmf, chV, chI);
    k_sel16<<<(N*64)/256, 256, 0, stream>>>(xf, nrmf, chV, chI, topIdx, ewArr);

    k_deg_init<<<N/256, 256, 0, stream>>>(degD);
    k_deg_scatter<<<NE/256, 256, 0, stream>>>(topIdx, ewArr, degD);
    k_dinv<<<N/256, 256, 0, stream>>>(degD, dinv);

    k_gemm1<<<(N*H)/256, 256, 0, stream>>>(xf, w1f, h1);
    k_agg_init<H><<<(N*H)/256, 256, 0, stream>>>(h1, dinv, agg1);
    k_agg_scat<H><<<4096, 256, 0, stream>>>(topIdx, ewArr, dinv, h1, agg1);
    k_post128<<<N, H, 0, stream>>>(agg1, b1f, g1f, be1f, z1);

    k_gemm2<<<(N*O)/256, 256, 0, stream>>>(z1, w2f, h2);
    k_agg_init<O><<<(N*O)/256, 256, 0, stream>>>(h2, dinv, agg2);
    k_agg_scat<O><<<4096, 256, 0, stream>>>(topIdx, ewArr, dinv, h2, agg2);
    k_post64<<<N, O, 0, stream>>>(agg2, b2f, g2f, be2f, z2);

    k_proj<<<(N*D)/256, 256, 0, stream>>>(z2, wpf, bpf, z3);
    k_out<<<(OUT0+ETOT+255)/256, 256, 0, stream>>>(z3, topIdx, ewArr, d_out, flag);
}

// Round 17
// 418.725 us; speedup vs baseline: 5.2557x; 1.0498x over previous
//
#include <hip/hip_runtime.h>
#include <cstdint>
#include <climits>

#define N 8192
#define D 64
#define H 128
#define O 64
#define KNB 16
#define NE (N*KNB)        // 131072
#define ETOT (NE + N)     // 139264
#define OUT0 (N*D)        // 524288
#define NSPL 32           // j-splits (chunks)
#define JSPAN 256         // j's per chunk (N/NSPL)
#define JTILE 128         // j-rows staged in LDS per tile (32 KB)
#define TCH 8             // stored top-T per chunk (certificate depth)

__device__ __forceinline__ float bf2f(unsigned short u){
    union { unsigned int u; float f; } v; v.u = ((unsigned int)u) << 16; return v.f;
}
__device__ __forceinline__ unsigned short f2bf(float f){
    union { float f; unsigned int u; } v; v.f = f;
    unsigned int r = v.u + 0x7FFFu + ((v.u >> 16) & 1u);   // RNE
    return (unsigned short)(r >> 16);
}

#define PIN4(v) asm volatile("" : "+v"((v).x), "+v"((v).y), "+v"((v).z), "+v"((v).w))

// ---------------- dtype probe: 1=bf16 inputs, 0=fp32 inputs ----------------
__global__ void k_probe(const unsigned short* __restrict__ x, int* __restrict__ flag){
    __shared__ int cnt;
    if (threadIdx.x == 0) cnt = 0;
    __syncthreads();
    unsigned short u = x[2*threadIdx.x];
    int e = (u >> 7) & 0xFF;
    int ok = (u == 0) || (e >= 0x60 && e <= 0x85);
    unsigned long long m = __ballot(ok);
    if ((threadIdx.x & 63) == 0) atomicAdd(&cnt, __popcll(m));
    __syncthreads();
    if (threadIdx.x == 0) *flag = (cnt >= 128) ? 1 : 0;
}

// ---------------- x convert -> fp32 ----------------
__global__ void k_cvt(const void* __restrict__ src, float* __restrict__ dst,
                      int n, const int* __restrict__ flag){
    int i = blockIdx.x*256 + threadIdx.x;
    if (i >= n) return;
    if (*flag) dst[i] = bf2f(((const unsigned short*)src)[i]);
    else       dst[i] = ((const float*)src)[i];
}

// ---------------- fused param convert (10 tensors, one launch) ----------------
__global__ void k_cvtp(const void* s1, const void* s2, const void* s3, const void* s4,
                       const void* s5, const void* s6, const void* s7, const void* s8,
                       const void* s9, const void* s10,
                       float* d1, float* d2, float* d3, float* d4, float* d5,
                       float* d6, float* d7, float* d8, float* d9, float* d10,
                       const int* __restrict__ flag){
    int id = blockIdx.x*256 + threadIdx.x;
    const void* s; float* d; int off;
    if      (id <  8192){ s = s1;  d = d1;  off = id; }
    else if (id <  8320){ s = s2;  d = d2;  off = id - 8192; }
    else if (id <  8448){ s = s3;  d = d3;  off = id - 8320; }
    else if (id <  8576){ s = s4;  d = d4;  off = id - 8448; }
    else if (id < 16768){ s = s5;  d = d5;  off = id - 8576; }
    else if (id < 16832){ s = s6;  d = d6;  off = id - 16768; }
    else if (id < 16896){ s = s7;  d = d7;  off = id - 16832; }
    else if (id < 16960){ s = s8;  d = d8;  off = id - 16896; }
    else if (id < 21056){ s = s9;  d = d9;  off = id - 16960; }
    else if (id < 21120){ s = s10; d = d10; off = id - 21056; }
    else return;
    if (*flag) d[off] = bf2f(((const unsigned short*)s)[off]);
    else       d[off] = ((const float*)s)[off];
}

// ---------------- row norms: EXACT numpy fp32 pairwise semantics ----------------
__global__ void k_prep(const float* __restrict__ xf, float* __restrict__ nrmf){
    int i = blockIdx.x*64 + threadIdx.x;
    const float* xr = xf + i*D;
    float r[8];
    #pragma unroll
    for (int q = 0; q < 8; ++q) r[q] = __fmul_rn(xr[q], xr[q]);
    #pragma unroll
    for (int b = 8; b < 64; b += 8)
        #pragma unroll
        for (int q = 0; q < 8; ++q)
            r[q] = __fadd_rn(r[q], __fmul_rn(xr[b+q], xr[b+q]));
    float s = __fadd_rn(__fadd_rn(__fadd_rn(r[0],r[1]), __fadd_rn(r[2],r[3])),
                        __fadd_rn(__fadd_rn(r[4],r[5]), __fadd_rn(r[6],r[7])));
    nrmf[i] = __fsqrt_rn(s);
}

// =====================================================================
// Single-scan exact top-k with per-chunk top-8 certificate.
// k_scan8: top-8 (value,idx) per 256-j chunk per query, LDS-broadcast
// j-rows (round-15-proven: 225us, DS-return-bound at ~8cyc per
// broadcast ds_read_b128 — per-lane delivery is charged even for
// broadcast). ROUND-16 POST-MORTEM: the wave-uniform-global + s_load
// alternative was falsified AGAIN (VGPR=52: xi4 demoted + per-j global
// reloads despite amdgpu_waves_per_eu(4,4); 243us, FETCH 2x). The
// allocator will not keep a 64-VGPR per-lane array resident across a
// scalarized-load loop — that structure is closed. LDS version stays.
// CERTIFICATE (proven r15): elements not stored for chunk c rank below
// c's stored 8th; if no chunk's 8th outranks the provisional 16th, the
// 256-candidate union top-16 is exact. P(fire) ~ 3.7e-7/query; the
// serial lane-0 fallback is a correctness net that ~never executes.
// Sim chain (bitwise-stable, operand-source independent):
//   a = fma-chain k=0..63; den = fadd(fmul(ni,nj),1e-8); s = fdiv(a,den).
// =====================================================================

__global__ __launch_bounds__(256, 2) void k_scan8(const float* __restrict__ xf,
                                                  const float* __restrict__ nrmf,
                                                  float* __restrict__ chV,
                                                  int* __restrict__ chI){
    __shared__ float sB[JTILE*64];   // 32 KB j-row tile
    __shared__ float sN[JTILE];

    int tid = threadIdx.x;
    int grp = blockIdx.x & 31;        // 32 query groups of 256
    int split = blockIdx.x >> 5;      // 32 chunks
    int i = grp*256 + tid;
    int jbase = split*JSPAN;

    const float4* xip = (const float4*)(xf + (size_t)i*D);
    float4 xi4[16];
    #pragma unroll
    for (int c = 0; c < 16; ++c) xi4[c] = xip[c];
    #pragma unroll
    for (int c = 0; c < 16; ++c) PIN4(xi4[c]);
    float ni = nrmf[i];

    float lv[TCH]; int li[TCH];
    #pragma unroll
    for (int r = 0; r < TCH; ++r){ lv[r] = -3.0e38f; li[r] = INT_MAX; }

    for (int t = 0; t < JSPAN/JTILE; ++t){
        int jt = jbase + t*JTILE;
        __syncthreads();   // previous tile fully consumed
        #pragma unroll
        for (int u = 0; u < (JTILE*16)/256; ++u){
            int idx = u*256 + tid;
            ((float4*)sB)[idx] = ((const float4*)xf)[(size_t)jt*16 + idx];
        }
        if (tid < JTILE) sN[tid] = nrmf[jt + tid];
        __syncthreads();

        for (int jj = 0; jj < JTILE; ++jj){
            int j = jt + jj;
            const float4* B4 = (const float4*)(sB + jj*64);   // uniform -> broadcast
            float nj = sN[jj];
            float a = 0.0f;
            #pragma unroll
            for (int c = 0; c < 16; ++c){
                float4 b = B4[c]; float4 xa = xi4[c];
                a = __fmaf_rn(b.x, xa.x, a);
                a = __fmaf_rn(b.y, xa.y, a);
                a = __fmaf_rn(b.z, xa.z, a);
                a = __fmaf_rn(b.w, xa.w, a);
            }
            float den = __fadd_rn(__fmul_rn(ni, nj), 1e-8f);
            float thr = lv[TCH-1]*den;
            // conservative prefilter (margin >> fdiv rounding), exact recheck
            if (j != i && a > __fmaf_rn(fabsf(thr), -1e-6f, thr)){
                float s0 = __fdiv_rn(a, den);
                if (s0 > lv[TCH-1]){   // strict >: ties keep earlier idx (idx-asc rank)
                    lv[TCH-1] = s0; li[TCH-1] = j;
                    #pragma unroll
                    for (int r = TCH-1; r > 0; --r){
                        if (lv[r] > lv[r-1]){
                            float tv = lv[r]; lv[r] = lv[r-1]; lv[r-1] = tv;
                            int ti = li[r]; li[r] = li[r-1]; li[r-1] = ti;
                        }
                    }
                }
            }
        }
    }
    // transposed layout: [(split*TCH+r)*N + i] — coalesced store
    #pragma unroll
    for (int r = 0; r < TCH; ++r){
        chV[(size_t)(split*TCH + r)*N + i] = lv[r];
        chI[(size_t)(split*TCH + r)*N + i] = li[r];
    }
}

// ---- wave-per-query exact top-16 of the 256-candidate union ----
__global__ __launch_bounds__(256, 2) void k_sel16(const float* __restrict__ xf,
                                                  const float* __restrict__ nrmf,
                                                  const float* __restrict__ chV,
                                                  const int* __restrict__ chI,
                                                  int* __restrict__ topIdx,
                                                  float* __restrict__ ewArr){
    int q = (blockIdx.x*256 + threadIdx.x) >> 6;   // one wave per query
    int lane = threadIdx.x & 63;

    // load 4 slots per lane as order-preserving 64-bit keys
    unsigned long long okey[4], key[4];
    #pragma unroll
    for (int s = 0; s < 4; ++s){
        int slot = lane + 64*s;
        float v = chV[(size_t)slot*N + q];
        int  id = chI[(size_t)slot*N + q];
        unsigned int u = __float_as_uint(v);
        if ((u & 0x7FFFFFFFu) == 0u) u = 0u;              // -0 -> +0
        u = (u & 0x80000000u) ? ~u : (u | 0x80000000u);   // monotone float map
        unsigned long long kk = ((unsigned long long)u << 32)
                              | (unsigned long long)(unsigned int)(~(unsigned int)id);
        okey[s] = kk; key[s] = kk;
    }

    float wv[16]; int widx[16];
    unsigned long long k16 = 0ull;
    #pragma unroll
    for (int sel = 0; sel < KNB; ++sel){
        unsigned long long m = key[0] > key[1] ? key[0] : key[1];
        if (key[2] > m) m = key[2];
        if (key[3] > m) m = key[3];
        #pragma unroll
        for (int off = 32; off > 0; off >>= 1){
            unsigned long long o = __shfl_xor(m, off);
            if (o > m) m = o;
        }
        if      (key[0] == m) key[0] = 0ull;   // unique keys: exactly one owner
        else if (key[1] == m) key[1] = 0ull;
        else if (key[2] == m) key[2] = 0ull;
        else if (key[3] == m) key[3] = 0ull;
        unsigned int um = (unsigned int)(m >> 32);
        unsigned int ou = (um & 0x80000000u) ? (um & 0x7FFFFFFFu) : ~um;
        wv[sel]  = __uint_as_float(ou);
        widx[sel] = (int)~((unsigned int)m);
        k16 = m;
    }

    // certificate: does any chunk's stored 8th outrank the 16th selected?
    bool fl = false;
    #pragma unroll
    for (int s = 0; s < 4; ++s){
        int slot = lane + 64*s;
        if ((slot % TCH) == TCH-1 && okey[s] > k16) fl = true;
    }
    if (__ballot(fl) == 0ull){
        if (lane == 0){
            #pragma unroll
            for (int sel = 0; sel < KNB; ++sel){
                topIdx[q*KNB + sel] = widx[sel];
                ewArr [q*KNB + sel] = (wv[sel] > 0.5f) ? wv[sel] : 0.0f;
            }
        }
        return;
    }
    if (lane != 0) return;

    // ---- serial exact fallback (round-11 code; P(reach) ~ 3e-7/query) ----
    float lv[16]; int li[16];
    #pragma unroll
    for (int r = 0; r < 16; ++r){ lv[r] = -3.0e38f; li[r] = INT_MAX; }
    unsigned int flags = 0;
    for (int c = 0; c < NSPL; ++c){
        float v8 = chV[(size_t)(c*TCH + TCH-1)*N + q];
        int  i8 = chI[(size_t)(c*TCH + TCH-1)*N + q];
        if (v8 > wv[15] || (v8 == wv[15] && i8 < widx[15])) flags |= (1u << c);
    }
    const float4* xq4 = (const float4*)(xf + (size_t)q*D);
    float4 xq[16];
    #pragma unroll
    for (int c = 0; c < 16; ++c) xq[c] = xq4[c];
    float ni = nrmf[q];
    for (int c = 0; c < NSPL; ++c){
        if ((flags >> c) & 1u){
            for (int j = c*JSPAN; j < c*JSPAN + JSPAN; ++j){
                if (j == q) continue;
                const float4* b4 = (const float4*)(xf + (size_t)j*D);
                float a = 0.0f;
                #pragma unroll
                for (int k = 0; k < 16; ++k){
                    float4 b = b4[k]; float4 xa = xq[k];
                    a = __fmaf_rn(b.x, xa.x, a);
                    a = __fmaf_rn(b.y, xa.y, a);
                    a = __fmaf_rn(b.z, xa.z, a);
                    a = __fmaf_rn(b.w, xa.w, a);
                }
                float den = __fadd_rn(__fmul_rn(ni, nrmf[j]), 1e-8f);
                float s0 = __fdiv_rn(a, den);
                if (s0 > lv[15] || (s0 == lv[15] && j < li[15])){
                    lv[15] = s0; li[15] = j;
                    #pragma unroll
                    for (int k = 15; k > 0; --k){
                        if (lv[k] > lv[k-1] || (lv[k] == lv[k-1] && li[k] < li[k-1])){
                            float tv = lv[k]; lv[k] = lv[k-1]; lv[k-1] = tv;
                            int ti = li[k]; li[k] = li[k-1]; li[k-1] = ti;
                        }
                    }
                }
            }
        } else {
            #pragma unroll
            for (int r = 0; r < TCH; ++r){
                float v = chV[(size_t)(c*TCH + r)*N + q];
                int  id = chI[(size_t)(c*TCH + r)*N + q];
                if (v > lv[15] || (v == lv[15] && id < li[15])){
                    lv[15] = v; li[15] = id;
                    #pragma unroll
                    for (int k = 15; k > 0; --k){
                        if (lv[k] > lv[k-1] || (lv[k] == lv[k-1] && li[k] < li[k-1])){
                            float tv = lv[k]; lv[k] = lv[k-1]; lv[k-1] = tv;
                            int ti = li[k]; li[k] = li[k-1]; li[k-1] = ti;
                        }
                    }
                }
            }
        }
    }
    #pragma unroll
    for (int sel = 0; sel < KNB; ++sel){
        topIdx[q*KNB + sel] = li[sel];
        ewArr [q*KNB + sel] = (lv[sel] > 0.5f) ? lv[sel] : 0.0f;
    }
}

// ---------------- degree / dinv ----------------
__global__ void k_deg_init(double* __restrict__ degD){
    int j = blockIdx.x*blockDim.x + threadIdx.x;
    if (j < N) degD[j] = 2.0;
}
__global__ void k_deg_scatter(const int* __restrict__ topIdx, const float* __restrict__ ewArr,
                              double* __restrict__ degD){
    int e = blockIdx.x*blockDim.x + threadIdx.x;
    if (e < NE){
        float w = ewArr[e];
        if (w > 0.0f) atomicAdd(&degD[topIdx[e]], (double)w);
    }
}
__global__ void k_dinv(const double* __restrict__ degD, float* __restrict__ dinv){
    int j = blockIdx.x*blockDim.x + threadIdx.x;
    if (j < N) dinv[j] = (float)(1.0 / sqrt(degD[j]));
}

// ---------------- dense matmuls ----------------
__global__ void k_gemm1(const float* __restrict__ xf, const float* __restrict__ W1,
                        float* __restrict__ h1){
    int id = blockIdx.x*256 + threadIdx.x;
    int i = id >> 7; int f = id & (H-1);
    const float* xr = xf + i*D;
    float acc = 0.f;
    #pragma unroll
    for (int k = 0; k < D; ++k) acc += xr[k] * W1[k*H + f];
    h1[id] = acc;
}
__global__ void k_gemm2(const float* __restrict__ z1, const float* __restrict__ W2,
                        float* __restrict__ h2){
    int id = blockIdx.x*256 + threadIdx.x;
    int i = id >> 6; int f = id & (O-1);
    const float* zr = z1 + i*H;
    float acc = 0.f;
    #pragma unroll
    for (int k = 0; k < H; ++k) acc += zr[k] * W2[k*O + f];
    h2[id] = acc;
}
__global__ void k_proj(const float* __restrict__ z2, const float* __restrict__ Wp,
                       const float* __restrict__ bp, float* __restrict__ z3){
    int id = blockIdx.x*256 + threadIdx.x;
    int i = id >> 6; int f = id & (D-1);
    const float* zr = z2 + i*O;
    float acc = bp[f];
    #pragma unroll
    for (int k = 0; k < O; ++k) acc += zr[k] * Wp[k*D + f];
    z3[id] = acc;
}

// ---------------- GCN aggregation ----------------
template<int F>
__global__ void k_agg_init(const float* __restrict__ h, const float* __restrict__ dinv,
                           float* __restrict__ agg){
    int id = blockIdx.x*256 + threadIdx.x;
    int j = id / F;
    float dj = dinv[j];
    agg[id] = 2.f * dj * dj * h[id];
}
// Grid-stride, WAVE-per-edge (round-16-proven: saved ~34us vs 131072
// one-edge workgroups). w==0 exit wave-uniform; reads/atomics coalesced.
template<int F>
__global__ __launch_bounds__(256) void k_agg_scat(const int* __restrict__ topIdx,
                                                  const float* __restrict__ ewArr,
                                                  const float* __restrict__ dinv,
                                                  const float* __restrict__ h,
                                                  float* __restrict__ agg){
    int wid = threadIdx.x >> 6;
    int lane = threadIdx.x & 63;
    for (int e = blockIdx.x*4 + wid; e < NE; e += gridDim.x*4){
        float w = ewArr[e];
        if (w == 0.f) continue;
        int s = e >> 4;
        int dn = topIdx[e];
        float c = dinv[s] * w * dinv[dn];
        #pragma unroll
        for (int p = 0; p < F/64; ++p){
            int f = lane + 64*p;
            atomicAdd(&agg[dn*F + f], c * h[s*F + f]);
        }
    }
}

// ---------------- bias + relu + layernorm ----------------
__global__ void k_post128(const float* __restrict__ agg, const float* __restrict__ b,
                          const float* __restrict__ g, const float* __restrict__ be,
                          float* __restrict__ z){
    __shared__ double s2[2];
    __shared__ double s3[2];
    int i = blockIdx.x; int f = threadIdx.x;
    float v = agg[i*H + f] + b[f];
    v = v > 0.f ? v : 0.f;
    int wid = f >> 6;
    double d = (double)v;
    for (int off = 32; off > 0; off >>= 1) d += __shfl_xor(d, off);
    if ((f & 63) == 0) s2[wid] = d;
    __syncthreads();
    double mu = (s2[0] + s2[1]) * (1.0/128.0);
    double dv = (double)v - mu;
    double qq = dv * dv;
    for (int off = 32; off > 0; off >>= 1) qq += __shfl_xor(qq, off);
    if ((f & 63) == 0) s3[wid] = qq;
    __syncthreads();
    double var = (s3[0] + s3[1]) * (1.0/128.0);
    double rs = 1.0 / sqrt(var + 1e-5);
    z[i*H + f] = (float)(dv * rs * (double)g[f] + (double)be[f]);
}
__global__ void k_post64(const float* __restrict__ agg, const float* __restrict__ b,
                         const float* __restrict__ g, const float* __restrict__ be,
                         float* __restrict__ z){
    int i = blockIdx.x; int f = threadIdx.x;
    float v = agg[i*O + f] + b[f];
    v = v > 0.f ? v : 0.f;
    double d = (double)v;
    for (int off = 32; off > 0; off >>= 1) d += __shfl_xor(d, off);
    double mu = d * (1.0/64.0);
    double dv = (double)v - mu;
    double qq = dv * dv;
    for (int off = 32; off > 0; off >>= 1) qq += __shfl_xor(qq, off);
    double var = qq * (1.0/64.0);
    double rs = 1.0 / sqrt(var + 1e-5);
    z[i*O + f] = (float)(dv * rs * (double)g[f] + (double)be[f]);
}

// ---------------- fused output store + edges (flag-branched dtype) ----------------
__global__ void k_out(const float* __restrict__ z3, const int* __restrict__ topIdx,
                      const float* __restrict__ ewArr, void* __restrict__ outp,
                      const int* __restrict__ flag){
    int id = blockIdx.x*256 + threadIdx.x;
    if (id < OUT0){
        float v = z3[id];
        if (*flag) ((unsigned short*)outp)[id] = f2bf(v);
        else       ((float*)outp)[id] = v;
        return;
    }
    int e = id - OUT0;
    if (e >= ETOT) return;
    int s, dn; float w;
    if (e < NE){ s = e >> 4; dn = topIdx[e]; w = ewArr[e]; }
    else       { s = e - NE; dn = s;        w = 1.0f; }
    if (*flag){
        unsigned short* o = (unsigned short*)outp;
        o[OUT0 + e]          = f2bf((float)s);
        o[OUT0 + ETOT + e]   = f2bf((float)dn);
        o[OUT0 + 2*ETOT + e] = f2bf(w);
    } else {
        float* o = (float*)outp;
        o[OUT0 + e]          = (float)s;
        o[OUT0 + ETOT + e]   = (float)dn;
        o[OUT0 + 2*ETOT + e] = w;
    }
}

extern "C" void kernel_launch(void* const* d_in, const int* in_sizes, int n_in,
                              void* d_out, int out_size, void* d_ws, size_t ws_size,
                              hipStream_t stream){
    char* ws = (char*)d_ws;
    int*    flag   = (int*)   (ws + 0);
    float*  w1f    = (float*) (ws + 4096);
    float*  b1f    = (float*) (ws + 36864);
    float*  g1f    = (float*) (ws + 37376);
    float*  be1f   = (float*) (ws + 37888);
    float*  w2f    = (float*) (ws + 38400);
    float*  b2f    = (float*) (ws + 71168);
    float*  g2f    = (float*) (ws + 71424);
    float*  be2f   = (float*) (ws + 71680);
    float*  wpf    = (float*) (ws + 71936);
    float*  bpf    = (float*) (ws + 88320);
    float*  xf     = (float*) (ws + 98304);      // 2 MB          -> 2195456
    float*  nrmf   = (float*) (ws + 2195456);    // 32 KB         -> 2228224
    int*    topIdx = (int*)   (ws + 2260992);    // 512 KB        -> 2785280
    float*  ewArr  = (float*) (ws + 2785280);    // 512 KB        -> 3309568
    double* degD   = (double*)(ws + 3309568);    // 64 KB         -> 3375104
    float*  dinv   = (float*) (ws + 3375104);    // 32 KB         -> 3407872
    float*  h1     = (float*) (ws + 3407872);    // 4 MB          -> 7602176
    float*  agg1   = (float*) (ws + 7602176);    // 4 MB          -> 11796480
    float*  z1     = (float*) (ws + 11796480);   // 4 MB          -> 15990784
    float*  h2     = h1;
    float*  agg2   = agg1;
    float*  z2     = z1;
    float*  z3     = h1;

    // topk scratch overlaps h1/agg1/z1 (all dead until k_gemm1, which
    // launches after k_sel16): chV 8.39 MB @3407872, chI 8.39 MB
    // @11796480, end 20185088 — within ws (round 3 used ~37 MB here).
    float* chV = (float*)(ws + 3407872);
    int*   chI = (int*)  (ws + 11796480);

    k_probe<<<1, 256, 0, stream>>>((const unsigned short*)d_in[0], flag);
    k_cvt<<<(N*D+255)/256, 256, 0, stream>>>(d_in[0], xf,  N*D, flag);
    k_cvtp<<<(21120+255)/256, 256, 0, stream>>>(
        d_in[1], d_in[2], d_in[3], d_in[4], d_in[5],
        d_in[6], d_in[7], d_in[8], d_in[9], d_in[10],
        w1f, b1f, g1f, be1f, w2f, b2f, g2f, be2f, wpf, bpf, flag);

    k_prep<<<N/64, 64, 0, stream>>>(xf, nrmf);
    k_scan8<<<32*NSPL, 256, 0, stream>>>(xf, nrmf, chV, chI);
    k_sel16<<<(N*64)/256, 256, 0, stream>>>(xf, nrmf, chV, chI, topIdx, ewArr);

    k_deg_init<<<N/256, 256, 0, stream>>>(degD);
    k_deg_scatter<<<NE/256, 256, 0, stream>>>(topIdx, ewArr, degD);
    k_dinv<<<N/256, 256, 0, stream>>>(degD, dinv);

    k_gemm1<<<(N*H)/256, 256, 0, stream>>>(xf, w1f, h1);
    k_agg_init<H><<<(N*H)/256, 256, 0, stream>>>(h1, dinv, agg1);
    k_agg_scat<H><<<4096, 256, 0, stream>>>(topIdx, ewArr, dinv, h1, agg1);
    k_post128<<<N, H, 0, stream>>>(agg1, b1f, g1f, be1f, z1);

    k_gemm2<<<(N*O)/256, 256, 0, stream>>>(z1, w2f, h2);
    k_agg_init<O><<<(N*O)/256, 256, 0, stream>>>(h2, dinv, agg2);
    k_agg_scat<O><<<4096, 256, 0, stream>>>(topIdx, ewArr, dinv, h2, agg2);
    k_post64<<<N, O, 0, stream>>>(agg2, b2f, g2f, be2f, z2);

    k_proj<<<(N*D)/256, 256, 0, stream>>>(z2, wpf, bpf, z3);
    k_out<<<(OUT0+ETOT+255)/256, 256, 0, stream>>>(z3, topIdx, ewArr, d_out, flag);
}

// Round 18
// 402.171 us; speedup vs baseline: 5.4720x; 1.0412x over previous
//
#include <hip/hip_runtime.h>
#include <cstdint>
#include <climits>

#define N 8192
#define D 64
#define H 128
#define O 64
#define KNB 16
#define NE (N*KNB)        // 131072
#define ETOT (NE + N)     // 139264
#define OUT0 (N*D)        // 524288
#define NSPL 32           // j-splits (chunks)
#define JSPAN 256         // j's per chunk (N/NSPL)
#define JTILE 128         // j-rows staged in LDS per tile (32 KB)
#define TCH 8             // stored top-T per chunk (certificate depth)

__device__ __forceinline__ float bf2f(unsigned short u){
    union { unsigned int u; float f; } v; v.u = ((unsigned int)u) << 16; return v.f;
}
__device__ __forceinline__ unsigned short f2bf(float f){
    union { float f; unsigned int u; } v; v.f = f;
    unsigned int r = v.u + 0x7FFFu + ((v.u >> 16) & 1u);   // RNE
    return (unsigned short)(r >> 16);
}

#define PIN4(v) asm volatile("" : "+v"((v).x), "+v"((v).y), "+v"((v).z), "+v"((v).w))

// ---------------- dtype probe: 1=bf16 inputs, 0=fp32 inputs ----------------
__global__ void k_probe(const unsigned short* __restrict__ x, int* __restrict__ flag){
    __shared__ int cnt;
    if (threadIdx.x == 0) cnt = 0;
    __syncthreads();
    unsigned short u = x[2*threadIdx.x];
    int e = (u >> 7) & 0xFF;
    int ok = (u == 0) || (e >= 0x60 && e <= 0x85);
    unsigned long long m = __ballot(ok);
    if ((threadIdx.x & 63) == 0) atomicAdd(&cnt, __popcll(m));
    __syncthreads();
    if (threadIdx.x == 0) *flag = (cnt >= 128) ? 1 : 0;
}

// ---------------- x convert -> fp32 ----------------
__global__ void k_cvt(const void* __restrict__ src, float* __restrict__ dst,
                      int n, const int* __restrict__ flag){
    int i = blockIdx.x*256 + threadIdx.x;
    if (i >= n) return;
    if (*flag) dst[i] = bf2f(((const unsigned short*)src)[i]);
    else       dst[i] = ((const float*)src)[i];
}

// ---------------- fused param convert (10 tensors, one launch) ----------------
__global__ void k_cvtp(const void* s1, const void* s2, const void* s3, const void* s4,
                       const void* s5, const void* s6, const void* s7, const void* s8,
                       const void* s9, const void* s10,
                       float* d1, float* d2, float* d3, float* d4, float* d5,
                       float* d6, float* d7, float* d8, float* d9, float* d10,
                       const int* __restrict__ flag){
    int id = blockIdx.x*256 + threadIdx.x;
    const void* s; float* d; int off;
    if      (id <  8192){ s = s1;  d = d1;  off = id; }
    else if (id <  8320){ s = s2;  d = d2;  off = id - 8192; }
    else if (id <  8448){ s = s3;  d = d3;  off = id - 8320; }
    else if (id <  8576){ s = s4;  d = d4;  off = id - 8448; }
    else if (id < 16768){ s = s5;  d = d5;  off = id - 8576; }
    else if (id < 16832){ s = s6;  d = d6;  off = id - 16768; }
    else if (id < 16896){ s = s7;  d = d7;  off = id - 16832; }
    else if (id < 16960){ s = s8;  d = d8;  off = id - 16896; }
    else if (id < 21056){ s = s9;  d = d9;  off = id - 16960; }
    else if (id < 21120){ s = s10; d = d10; off = id - 21056; }
    else return;
    if (*flag) d[off] = bf2f(((const unsigned short*)s)[off]);
    else       d[off] = ((const float*)s)[off];
}

// ---------------- row norms: EXACT numpy fp32 pairwise semantics ----------------
__global__ void k_prep(const float* __restrict__ xf, float* __restrict__ nrmf){
    int i = blockIdx.x*64 + threadIdx.x;
    const float* xr = xf + i*D;
    float r[8];
    #pragma unroll
    for (int q = 0; q < 8; ++q) r[q] = __fmul_rn(xr[q], xr[q]);
    #pragma unroll
    for (int b = 8; b < 64; b += 8)
        #pragma unroll
        for (int q = 0; q < 8; ++q)
            r[q] = __fadd_rn(r[q], __fmul_rn(xr[b+q], xr[b+q]));
    float s = __fadd_rn(__fadd_rn(__fadd_rn(r[0],r[1]), __fadd_rn(r[2],r[3])),
                        __fadd_rn(__fadd_rn(r[4],r[5]), __fadd_rn(r[6],r[7])));
    nrmf[i] = __fsqrt_rn(s);
}

// =====================================================================
// Single-scan exact top-k with per-chunk top-8 certificate.
// k_scan8: LDS-broadcast j-rows, top-8 per 256-j chunk. MEASURED AT THE
// LDS-BW ROOFLINE: 2.1 cyc/(q,j) vs 2.0 theoretical (256B of B-row per
// (q,j) through 128B/cyc LDS). Register/SGPR operand sourcing falsified
// in r5/r6/r16 (allocator demotes the 64-VGPR query row, always).
// CERTIFICATE (proven r15): elements not stored for chunk c rank below
// c's stored 8th; if no chunk's 8th outranks the provisional 16th, the
// 256-candidate union top-16 is exact. P(fire) ~ 3.7e-7/query; serial
// lane-0 fallback is a correctness net that ~never executes.
// Sim chain (bitwise-stable, operand-source independent):
//   a = fma-chain k=0..63; den = fadd(fmul(ni,nj),1e-8); s = fdiv(a,den).
// ROUND-18 FUSIONS (launch/pass trim, no algorithmic change): degree
// atomics folded into k_sel16 (k_deg_scatter deleted; identical edge
// set); agg self-loop init folded into gemm epilogues (k_agg_init
// deleted); projection folded into k_out (k_proj deleted).
// =====================================================================

__global__ __launch_bounds__(256, 2) void k_scan8(const float* __restrict__ xf,
                                                  const float* __restrict__ nrmf,
                                                  float* __restrict__ chV,
                                                  int* __restrict__ chI){
    __shared__ float sB[JTILE*64];   // 32 KB j-row tile
    __shared__ float sN[JTILE];

    int tid = threadIdx.x;
    int grp = blockIdx.x & 31;        // 32 query groups of 256
    int split = blockIdx.x >> 5;      // 32 chunks
    int i = grp*256 + tid;
    int jbase = split*JSPAN;

    const float4* xip = (const float4*)(xf + (size_t)i*D);
    float4 xi4[16];
    #pragma unroll
    for (int c = 0; c < 16; ++c) xi4[c] = xip[c];
    #pragma unroll
    for (int c = 0; c < 16; ++c) PIN4(xi4[c]);
    float ni = nrmf[i];

    float lv[TCH]; int li[TCH];
    #pragma unroll
    for (int r = 0; r < TCH; ++r){ lv[r] = -3.0e38f; li[r] = INT_MAX; }

    for (int t = 0; t < JSPAN/JTILE; ++t){
        int jt = jbase + t*JTILE;
        __syncthreads();   // previous tile fully consumed
        #pragma unroll
        for (int u = 0; u < (JTILE*16)/256; ++u){
            int idx = u*256 + tid;
            ((float4*)sB)[idx] = ((const float4*)xf)[(size_t)jt*16 + idx];
        }
        if (tid < JTILE) sN[tid] = nrmf[jt + tid];
        __syncthreads();

        for (int jj = 0; jj < JTILE; ++jj){
            int j = jt + jj;
            const float4* B4 = (const float4*)(sB + jj*64);   // uniform -> broadcast
            float nj = sN[jj];
            float a = 0.0f;
            #pragma unroll
            for (int c = 0; c < 16; ++c){
                float4 b = B4[c]; float4 xa = xi4[c];
                a = __fmaf_rn(b.x, xa.x, a);
                a = __fmaf_rn(b.y, xa.y, a);
                a = __fmaf_rn(b.z, xa.z, a);
                a = __fmaf_rn(b.w, xa.w, a);
            }
            float den = __fadd_rn(__fmul_rn(ni, nj), 1e-8f);
            float thr = lv[TCH-1]*den;
            // conservative prefilter (margin >> fdiv rounding), exact recheck
            if (j != i && a > __fmaf_rn(fabsf(thr), -1e-6f, thr)){
                float s0 = __fdiv_rn(a, den);
                if (s0 > lv[TCH-1]){   // strict >: ties keep earlier idx (idx-asc rank)
                    lv[TCH-1] = s0; li[TCH-1] = j;
                    #pragma unroll
                    for (int r = TCH-1; r > 0; --r){
                        if (lv[r] > lv[r-1]){
                            float tv = lv[r]; lv[r] = lv[r-1]; lv[r-1] = tv;
                            int ti = li[r]; li[r] = li[r-1]; li[r-1] = ti;
                        }
                    }
                }
            }
        }
    }
    // transposed layout: [(split*TCH+r)*N + i] — coalesced store
    #pragma unroll
    for (int r = 0; r < TCH; ++r){
        chV[(size_t)(split*TCH + r)*N + i] = lv[r];
        chI[(size_t)(split*TCH + r)*N + i] = li[r];
    }
}

// ---- wave-per-query exact top-16 of the 256-candidate union ----
// Also accumulates the weighted in-degree (fused former k_deg_scatter);
// degD must be pre-initialized to 2.0 (k_deg_init runs before k_scan8).
__global__ __launch_bounds__(256, 2) void k_sel16(const float* __restrict__ xf,
                                                  const float* __restrict__ nrmf,
                                                  const float* __restrict__ chV,
                                                  const int* __restrict__ chI,
                                                  int* __restrict__ topIdx,
                                                  float* __restrict__ ewArr,
                                                  double* __restrict__ degD){
    int q = (blockIdx.x*256 + threadIdx.x) >> 6;   // one wave per query
    int lane = threadIdx.x & 63;

    // load 4 slots per lane as order-preserving 64-bit keys
    unsigned long long okey[4], key[4];
    #pragma unroll
    for (int s = 0; s < 4; ++s){
        int slot = lane + 64*s;
        float v = chV[(size_t)slot*N + q];
        int  id = chI[(size_t)slot*N + q];
        unsigned int u = __float_as_uint(v);
        if ((u & 0x7FFFFFFFu) == 0u) u = 0u;              // -0 -> +0
        u = (u & 0x80000000u) ? ~u : (u | 0x80000000u);   // monotone float map
        unsigned long long kk = ((unsigned long long)u << 32)
                              | (unsigned long long)(unsigned int)(~(unsigned int)id);
        okey[s] = kk; key[s] = kk;
    }

    float wv[16]; int widx[16];
    unsigned long long k16 = 0ull;
    #pragma unroll
    for (int sel = 0; sel < KNB; ++sel){
        unsigned long long m = key[0] > key[1] ? key[0] : key[1];
        if (key[2] > m) m = key[2];
        if (key[3] > m) m = key[3];
        #pragma unroll
        for (int off = 32; off > 0; off >>= 1){
            unsigned long long o = __shfl_xor(m, off);
            if (o > m) m = o;
        }
        if      (key[0] == m) key[0] = 0ull;   // unique keys: exactly one owner
        else if (key[1] == m) key[1] = 0ull;
        else if (key[2] == m) key[2] = 0ull;
        else if (key[3] == m) key[3] = 0ull;
        unsigned int um = (unsigned int)(m >> 32);
        unsigned int ou = (um & 0x80000000u) ? (um & 0x7FFFFFFFu) : ~um;
        wv[sel]  = __uint_as_float(ou);
        widx[sel] = (int)~((unsigned int)m);
        k16 = m;
    }

    // certificate: does any chunk's stored 8th outrank the 16th selected?
    bool fl = false;
    #pragma unroll
    for (int s = 0; s < 4; ++s){
        int slot = lane + 64*s;
        if ((slot % TCH) == TCH-1 && okey[s] > k16) fl = true;
    }
    if (__ballot(fl) == 0ull){
        if (lane == 0){
            #pragma unroll
            for (int sel = 0; sel < KNB; ++sel){
                float w = (wv[sel] > 0.5f) ? wv[sel] : 0.0f;
                topIdx[q*KNB + sel] = widx[sel];
                ewArr [q*KNB + sel] = w;
                if (w > 0.0f) atomicAdd(&degD[widx[sel]], (double)w);
            }
        }
        return;
    }
    if (lane != 0) return;

    // ---- serial exact fallback (round-11 code; P(reach) ~ 3e-7/query) ----
    float lv[16]; int li[16];
    #pragma unroll
    for (int r = 0; r < 16; ++r){ lv[r] = -3.0e38f; li[r] = INT_MAX; }
    unsigned int flags = 0;
    for (int c = 0; c < NSPL; ++c){
        float v8 = chV[(size_t)(c*TCH + TCH-1)*N + q];
        int  i8 = chI[(size_t)(c*TCH + TCH-1)*N + q];
        if (v8 > wv[15] || (v8 == wv[15] && i8 < widx[15])) flags |= (1u << c);
    }
    const float4* xq4 = (const float4*)(xf + (size_t)q*D);
    float4 xq[16];
    #pragma unroll
    for (int c = 0; c < 16; ++c) xq[c] = xq4[c];
    float ni = nrmf[q];
    for (int c = 0; c < NSPL; ++c){
        if ((flags >> c) & 1u){
            for (int j = c*JSPAN; j < c*JSPAN + JSPAN; ++j){
                if (j == q) continue;
                const float4* b4 = (const float4*)(xf + (size_t)j*D);
                float a = 0.0f;
                #pragma unroll
                for (int k = 0; k < 16; ++k){
                    float4 b = b4[k]; float4 xa = xq[k];
                    a = __fmaf_rn(b.x, xa.x, a);
                    a = __fmaf_rn(b.y, xa.y, a);
                    a = __fmaf_rn(b.z, xa.z, a);
                    a = __fmaf_rn(b.w, xa.w, a);
                }
                float den = __fadd_rn(__fmul_rn(ni, nrmf[j]), 1e-8f);
                float s0 = __fdiv_rn(a, den);
                if (s0 > lv[15] || (s0 == lv[15] && j < li[15])){
                    lv[15] = s0; li[15] = j;
                    #pragma unroll
                    for (int k = 15; k > 0; --k){
                        if (lv[k] > lv[k-1] || (lv[k] == lv[k-1] && li[k] < li[k-1])){
                            float tv = lv[k]; lv[k] = lv[k-1]; lv[k-1] = tv;
                            int ti = li[k]; li[k] = li[k-1]; li[k-1] = ti;
                        }
                    }
                }
            }
        } else {
            #pragma unroll
            for (int r = 0; r < TCH; ++r){
                float v = chV[(size_t)(c*TCH + r)*N + q];
                int  id = chI[(size_t)(c*TCH + r)*N + q];
                if (v > lv[15] || (v == lv[15] && id < li[15])){
                    lv[15] = v; li[15] = id;
                    #pragma unroll
                    for (int k = 15; k > 0; --k){
                        if (lv[k] > lv[k-1] || (lv[k] == lv[k-1] && li[k] < li[k-1])){
                            float tv = lv[k]; lv[k] = lv[k-1]; lv[k-1] = tv;
                            int ti = li[k]; li[k] = li[k-1]; li[k-1] = ti;
                        }
                    }
                }
            }
        }
    }
    #pragma unroll
    for (int sel = 0; sel < KNB; ++sel){
        float w = (lv[sel] > 0.5f) ? lv[sel] : 0.0f;
        topIdx[q*KNB + sel] = li[sel];
        ewArr [q*KNB + sel] = w;
        if (w > 0.0f) atomicAdd(&degD[li[sel]], (double)w);
    }
}

// ---------------- degree / dinv ----------------
__global__ void k_deg_init(double* __restrict__ degD){
    int j = blockIdx.x*blockDim.x + threadIdx.x;
    if (j < N) degD[j] = 2.0;
}
__global__ void k_dinv(const double* __restrict__ degD, float* __restrict__ dinv){
    int j = blockIdx.x*blockDim.x + threadIdx.x;
    if (j < N) dinv[j] = (float)(1.0 / sqrt(degD[j]));
}

// ---------------- dense matmuls (fused agg self-loop init) ----------------
__global__ void k_gemm1(const float* __restrict__ xf, const float* __restrict__ W1,
                        const float* __restrict__ dinv,
                        float* __restrict__ h1, float* __restrict__ agg){
    int id = blockIdx.x*256 + threadIdx.x;
    int i = id >> 7; int f = id & (H-1);
    const float* xr = xf + i*D;
    float acc = 0.f;
    #pragma unroll
    for (int k = 0; k < D; ++k) acc += xr[k] * W1[k*H + f];
    h1[id] = acc;
    float dj = dinv[i];
    agg[id] = 2.f * dj * dj * acc;
}
__global__ void k_gemm2(const float* __restrict__ z1, const float* __restrict__ W2,
                        const float* __restrict__ dinv,
                        float* __restrict__ h2, float* __restrict__ agg){
    int id = blockIdx.x*256 + threadIdx.x;
    int i = id >> 6; int f = id & (O-1);
    const float* zr = z1 + i*H;
    float acc = 0.f;
    #pragma unroll
    for (int k = 0; k < H; ++k) acc += zr[k] * W2[k*O + f];
    h2[id] = acc;
    float dj = dinv[i];
    agg[id] = 2.f * dj * dj * acc;
}

// ---------------- GCN aggregation ----------------
// Grid-stride, WAVE-per-edge (round-16-proven: saved ~34us vs 131072
// one-edge workgroups). w==0 exit wave-uniform; reads/atomics coalesced.
template<int F>
__global__ __launch_bounds__(256) void k_agg_scat(const int* __restrict__ topIdx,
                                                  const float* __restrict__ ewArr,
                                                  const float* __restrict__ dinv,
                                                  const float* __restrict__ h,
                                                  float* __restrict__ agg){
    int wid = threadIdx.x >> 6;
    int lane = threadIdx.x & 63;
    for (int e = blockIdx.x*4 + wid; e < NE; e += gridDim.x*4){
        float w = ewArr[e];
        if (w == 0.f) continue;
        int s = e >> 4;
        int dn = topIdx[e];
        float c = dinv[s] * w * dinv[dn];
        #pragma unroll
        for (int p = 0; p < F/64; ++p){
            int f = lane + 64*p;
            atomicAdd(&agg[dn*F + f], c * h[s*F + f]);
        }
    }
}

// ---------------- bias + relu + layernorm ----------------
__global__ void k_post128(const float* __restrict__ agg, const float* __restrict__ b,
                          const float* __restrict__ g, const float* __restrict__ be,
                          float* __restrict__ z){
    __shared__ double s2[2];
    __shared__ double s3[2];
    int i = blockIdx.x; int f = threadIdx.x;
    float v = agg[i*H + f] + b[f];
    v = v > 0.f ? v : 0.f;
    int wid = f >> 6;
    double d = (double)v;
    for (int off = 32; off > 0; off >>= 1) d += __shfl_xor(d, off);
    if ((f & 63) == 0) s2[wid] = d;
    __syncthreads();
    double mu = (s2[0] + s2[1]) * (1.0/128.0);
    double dv = (double)v - mu;
    double qq = dv * dv;
    for (int off = 32; off > 0; off >>= 1) qq += __shfl_xor(qq, off);
    if ((f & 63) == 0) s3[wid] = qq;
    __syncthreads();
    double var = (s3[0] + s3[1]) * (1.0/128.0);
    double rs = 1.0 / sqrt(var + 1e-5);
    z[i*H + f] = (float)(dv * rs * (double)g[f] + (double)be[f]);
}
__global__ void k_post64(const float* __restrict__ agg, const float* __restrict__ b,
                         const float* __restrict__ g, const float* __restrict__ be,
                         float* __restrict__ z){
    int i = blockIdx.x; int f = threadIdx.x;
    float v = agg[i*O + f] + b[f];
    v = v > 0.f ? v : 0.f;
    double d = (double)v;
    for (int off = 32; off > 0; off >>= 1) d += __shfl_xor(d, off);
    double mu = d * (1.0/64.0);
    double dv = (double)v - mu;
    double qq = dv * dv;
    for (int off = 32; off > 0; off >>= 1) qq += __shfl_xor(qq, off);
    double var = qq * (1.0/64.0);
    double rs = 1.0 / sqrt(var + 1e-5);
    z[i*O + f] = (float)(dv * rs * (double)g[f] + (double)be[f]);
}

// ---------------- fused projection + output store + edges ----------------
__global__ void k_out(const float* __restrict__ z2, const float* __restrict__ Wp,
                      const float* __restrict__ bp, const int* __restrict__ topIdx,
                      const float* __restrict__ ewArr, void* __restrict__ outp,
                      const int* __restrict__ flag){
    int id = blockIdx.x*256 + threadIdx.x;
    if (id < OUT0){
        int i = id >> 6; int f = id & (D-1);
        const float* zr = z2 + i*O;
        float acc = bp[f];
        #pragma unroll
        for (int k = 0; k < O; ++k) acc += zr[k] * Wp[k*D + f];
        if (*flag) ((unsigned short*)outp)[id] = f2bf(acc);
        else       ((float*)outp)[id] = acc;
        return;
    }
    int e = id - OUT0;
    if (e >= ETOT) return;
    int s, dn; float w;
    if (e < NE){ s = e >> 4; dn = topIdx[e]; w = ewArr[e]; }
    else       { s = e - NE; dn = s;        w = 1.0f; }
    if (*flag){
        unsigned short* o = (unsigned short*)outp;
        o[OUT0 + e]          = f2bf((float)s);
        o[OUT0 + ETOT + e]   = f2bf((float)dn);
        o[OUT0 + 2*ETOT + e] = f2bf(w);
    } else {
        float* o = (float*)outp;
        o[OUT0 + e]          = (float)s;
        o[OUT0 + ETOT + e]   = (float)dn;
        o[OUT0 + 2*ETOT + e] = w;
    }
}

extern "C" void kernel_launch(void* const* d_in, const int* in_sizes, int n_in,
                              void* d_out, int out_size, void* d_ws, size_t ws_size,
                              hipStream_t stream){
    char* ws = (char*)d_ws;
    int*    flag   = (int*)   (ws + 0);
    float*  w1f    = (float*) (ws + 4096);
    float*  b1f    = (float*) (ws + 36864);
    float*  g1f    = (float*) (ws + 37376);
    float*  be1f   = (float*) (ws + 37888);
    float*  w2f    = (float*) (ws + 38400);
    float*  b2f    = (float*) (ws + 71168);
    float*  g2f    = (float*) (ws + 71424);
    float*  be2f   = (float*) (ws + 71680);
    float*  wpf    = (float*) (ws + 71936);
    float*  bpf    = (float*) (ws + 88320);
    float*  xf     = (float*) (ws + 98304);      // 2 MB          -> 2195456
    float*  nrmf   = (float*) (ws + 2195456);    // 32 KB         -> 2228224
    int*    topIdx = (int*)   (ws + 2260992);    // 512 KB        -> 2785280
    float*  ewArr  = (float*) (ws + 2785280);    // 512 KB        -> 3309568
    double* degD   = (double*)(ws + 3309568);    // 64 KB         -> 3375104
    float*  dinv   = (float*) (ws + 3375104);    // 32 KB         -> 3407872
    float*  h1     = (float*) (ws + 3407872);    // 4 MB          -> 7602176
    float*  agg1   = (float*) (ws + 7602176);    // 4 MB          -> 11796480
    float*  z1     = (float*) (ws + 11796480);   // 4 MB          -> 15990784
    float*  h2     = h1;
    float*  agg2   = agg1;
    float*  z2     = z1;

    // topk scratch overlaps h1/agg1/z1 (all dead until k_gemm1, which
    // launches after k_sel16): chV 8.39 MB @3407872, chI 8.39 MB
    // @11796480, end 20185088 — within ws (round 3 used ~37 MB here).
    float* chV = (float*)(ws + 3407872);
    int*   chI = (int*)  (ws + 11796480);

    k_probe<<<1, 256, 0, stream>>>((const unsigned short*)d_in[0], flag);
    k_cvt<<<(N*D+255)/256, 256, 0, stream>>>(d_in[0], xf,  N*D, flag);
    k_cvtp<<<(21120+255)/256, 256, 0, stream>>>(
        d_in[1], d_in[2], d_in[3], d_in[4], d_in[5],
        d_in[6], d_in[7], d_in[8], d_in[9], d_in[10],
        w1f, b1f, g1f, be1f, w2f, b2f, g2f, be2f, wpf, bpf, flag);

    k_prep<<<N/64, 64, 0, stream>>>(xf, nrmf);
    k_deg_init<<<N/256, 256, 0, stream>>>(degD);
    k_scan8<<<32*NSPL, 256, 0, stream>>>(xf, nrmf, chV, chI);
    k_sel16<<<(N*64)/256, 256, 0, stream>>>(xf, nrmf, chV, chI, topIdx, ewArr, degD);
    k_dinv<<<N/256, 256, 0, stream>>>(degD, dinv);

    k_gemm1<<<(N*H)/256, 256, 0, stream>>>(xf, w1f, dinv, h1, agg1);
    k_agg_scat<H><<<4096, 256, 0, stream>>>(topIdx, ewArr, dinv, h1, agg1);
    k_post128<<<N, H, 0, stream>>>(agg1, b1f, g1f, be1f, z1);

    k_gemm2<<<(N*O)/256, 256, 0, stream>>>(z1, w2f, dinv, h2, agg2);
    k_agg_scat<O><<<4096, 256, 0, stream>>>(topIdx, ewArr, dinv, h2, agg2);
    k_post64<<<N, O, 0, stream>>>(agg2, b2f, g2f, be2f, z2);

    k_out<<<(OUT0+ETOT+255)/256, 256, 0, stream>>>(z2, wpf, bpf, topIdx, ewArr,
                                                   d_out, flag);
}